// Round 6
// baseline (874.077 us; speedup 1.0000x reference)
//
#include <hip/hip_runtime.h>

#define H_  1024
#define W_  1024
#define HW_ (H_*W_)
#define M_  524288

#define SWZ(a) ((a) + ((a)>>4))

// ---------------------------------------------------------------- complex mul
__device__ __forceinline__ float2 cmulf(float2 a, float2 b){
  return make_float2(fmaf(a.x,b.x,-(a.y*b.y)), fmaf(a.x,b.y,a.y*b.x));
}

// ---------------------------------------------------------------- radix-4 bfly
template<int DIR>
__device__ __forceinline__ void bfly4(float2 v[4], int j, int Ns){
  if (Ns>1){
    float ang = ((DIR>0)?6.28318530717958647692f:-6.28318530717958647692f)
                * (float)(j&(Ns-1)) / (float)(4*Ns);
    float s,c; __sincosf(ang,&s,&c);
    float2 w1=make_float2(c,s);
    float2 w2=cmulf(w1,w1);
    float2 w3=cmulf(w2,w1);
    v[1]=cmulf(v[1],w1); v[2]=cmulf(v[2],w2); v[3]=cmulf(v[3],w3);
  }
  float2 t0=make_float2(v[0].x+v[2].x, v[0].y+v[2].y);
  float2 t2=make_float2(v[0].x-v[2].x, v[0].y-v[2].y);
  float2 t1=make_float2(v[1].x+v[3].x, v[1].y+v[3].y);
  float2 t3=make_float2(v[1].x-v[3].x, v[1].y-v[3].y);
  float2 t3r=(DIR<0)?make_float2(t3.y,-t3.x):make_float2(-t3.y,t3.x);
  v[0]=make_float2(t0.x+t1.x,  t0.y+t1.y);
  v[1]=make_float2(t2.x+t3r.x, t2.y+t3r.y);
  v[2]=make_float2(t0.x-t1.x,  t0.y-t1.y);
  v[3]=make_float2(t2.x-t3r.x, t2.y-t3r.y);
}

template<int DIR, int NS>
__device__ __forceinline__ void fft_stage(int j, const float2* src, float2* dst){
  float2 v[4];
#pragma unroll
  for(int r=0;r<4;r++) v[r]=src[SWZ(j+256*r)];
  bfly4<DIR>(v,j,NS);
  int base = ((j & ~(NS-1))<<2) | (j&(NS-1));
#pragma unroll
  for(int r=0;r<4;r++) dst[SWZ(base+NS*r)]=v[r];
}

template<int DIR>
__device__ __forceinline__ void fft1024_core(float2 v[4], int j, float2* A, float2* B, float scale){
  bfly4<DIR>(v,j,1);
#pragma unroll
  for(int r=0;r<4;r++) A[SWZ(4*j+r)]=v[r];
  __syncthreads();
  fft_stage<DIR,4 >(j,A,B); __syncthreads();
  fft_stage<DIR,16>(j,B,A); __syncthreads();
  fft_stage<DIR,64>(j,A,B); __syncthreads();
#pragma unroll
  for(int r=0;r<4;r++) v[r]=B[SWZ(j+256*r)];
  bfly4<DIR>(v,j,256);
#pragma unroll
  for(int r=0;r<4;r++){ v[r].x*=scale; v[r].y*=scale; }
}

template<int DIR>
__global__ __launch_bounds__(256) void k_fft_rows(const float2* src, float2* dst, float scale){
  __shared__ float2 A[1088], B[1088];
  int j = threadIdx.x;
  const float2* s = src + (size_t)blockIdx.x*W_;
  float2 v[4];
#pragma unroll
  for(int r=0;r<4;r++) v[r]=s[j+256*r];
  fft1024_core<DIR>(v,j,A,B,scale);
  float2* d = dst + (size_t)blockIdx.x*W_;
#pragma unroll
  for(int r=0;r<4;r++) d[j+256*r]=v[r];
}

template<int DIR>
__global__ __launch_bounds__(256) void k_fft_cols(float2* data, float scale){
  __shared__ float2 T[4*1025];
  __shared__ float2 A[1088], B[1088];
  int tid=threadIdx.x, c0=blockIdx.x*4;
#pragma unroll
  for(int k=0;k<16;k++){
    int idx=tid+256*k; int c=idx&3, r=idx>>2;
    T[c*1025+r]=data[(size_t)r*W_ + c0 + c];
  }
  __syncthreads();
  for(int c=0;c<4;c++){
    float2* col = T + c*1025;
    float2 v[4];
#pragma unroll
    for(int r=0;r<4;r++) v[r]=col[tid+256*r];
    fft1024_core<DIR>(v,tid,A,B,scale);
#pragma unroll
    for(int r=0;r<4;r++) col[tid+256*r]=v[r];
  }
  __syncthreads();
#pragma unroll
  for(int k=0;k<16;k++){
    int idx=tid+256*k; int c=idx&3, r=idx>>2;
    data[(size_t)r*W_ + c0 + c]=T[c*1025+r];
  }
}

// ---------------------------------------------------------------- interp helpers
__device__ __forceinline__ void corners(float kx, float ky, int idx[4], float w[4]){
  float gx = kx*1024.f, gy = ky*1024.f;
  float fx = floorf(gx), fy = floorf(gy);
  float tx = gx-fx, ty = gy-fy;
  int ix = ((int)fx)&1023, iy = ((int)fy)&1023;
  int ix1=(ix+1)&1023, iy1=(iy+1)&1023;
  idx[0]=(ix<<10)|iy;  idx[1]=(ix1<<10)|iy;
  idx[2]=(ix<<10)|iy1; idx[3]=(ix1<<10)|iy1;
  float ux=1.f-tx, uy=1.f-ty;
  w[0]=ux*uy; w[1]=tx*uy; w[2]=ux*ty; w[3]=tx*ty;
}

// ---------------------------------------------------------------- init
__global__ __launch_bounds__(256) void k_pack(const float* xr, const float* xi, float2* X, float* t){
  int i = blockIdx.x*256+threadIdx.x;
  if (i<HW_) X[i]=make_float2(xr[i],xi[i]);
  if (blockIdx.x==0 && threadIdx.x<32) t[threadIdx.x]=0.f;
}

__global__ __launch_bounds__(256) void k_hist(const float* kt, int* counts, float* pmax){
  int m = blockIdx.x*256+threadIdx.x;
  float r = 0.f;
  {
    float kx=kt[2*m], ky=kt[2*m+1];
    float dx=kx-0.5f, dy=ky-0.5f;
    r = sqrtf(dx*dx+dy*dy);
    int ix = ((int)floorf(kx*1024.f))&1023;
    int iy = ((int)floorf(ky*1024.f))&1023;
    atomicAdd(&counts[(ix<<10)|iy],1);
  }
  for(int o=32;o>0;o>>=1) r = fmaxf(r, __shfl_down(r,o,64));
  __shared__ float sm[4];
  if((threadIdx.x&63)==0) sm[threadIdx.x>>6]=r;
  __syncthreads();
  if(threadIdx.x==0)
    pmax[blockIdx.x] = fmaxf(fmaxf(sm[0],sm[1]),fmaxf(sm[2],sm[3]));
}

__global__ __launch_bounds__(256) void k_reduce_max(const float* pmax, float* t){
  int tid=threadIdx.x;
  float s=-1e30f;
  for(int k=tid;k<2048;k+=256) s=fmaxf(s,pmax[k]);
  __shared__ float sm[4];
  for(int o=32;o>0;o>>=1) s=fmaxf(s,__shfl_down(s,o,64));
  if((tid&63)==0) sm[tid>>6]=s;
  __syncthreads();
  if(tid==0) t[15]=fmaxf(fmaxf(sm[0],sm[1]),fmaxf(sm[2],sm[3]));
}

// ---------------------------------------------------------------- scan
__global__ __launch_bounds__(256) void k_scan1(const int* cnt, int* off, int* bsum){
  __shared__ int sm[256];
  int base = blockIdx.x*1024;
  int tid = threadIdx.x;
  int4 c = *(const int4*)(cnt + base + tid*4);
  int s = c.x+c.y+c.z+c.w;
  sm[tid]=s; __syncthreads();
  int v=s;
  for(int o=1;o<256;o<<=1){
    int u = (tid>=o)? sm[tid-o]:0;
    __syncthreads();
    v += u; sm[tid]=v;
    __syncthreads();
  }
  int excl = v - s;
  int4 o4;
  o4.x=excl; o4.y=excl+c.x; o4.z=excl+c.x+c.y; o4.w=excl+c.x+c.y+c.z;
  *(int4*)(off+base+tid*4)=o4;
  if (tid==255) bsum[blockIdx.x]=v;
}

__global__ __launch_bounds__(256) void k_scan2(int* bsum){
  __shared__ int sm[256];
  int tid=threadIdx.x;
  int4 c = *(const int4*)(bsum + tid*4);
  int s = c.x+c.y+c.z+c.w;
  sm[tid]=s; __syncthreads();
  int v=s;
  for(int o=1;o<256;o<<=1){
    int u = (tid>=o)? sm[tid-o]:0;
    __syncthreads();
    v += u; sm[tid]=v;
    __syncthreads();
  }
  int excl=v-s;
  int4 o4;
  o4.x=excl; o4.y=excl+c.x; o4.z=excl+c.x+c.y; o4.w=excl+c.x+c.y+c.z;
  *(int4*)(bsum+tid*4)=o4;
}

__global__ __launch_bounds__(256) void k_scan3(int* off, const int* bbase){
  int gid = blockIdx.x*256+threadIdx.x;
  int b = bbase[gid>>8];
  int4 v = *(int4*)(off + gid*4);
  v.x+=b; v.y+=b; v.z+=b; v.w+=b;
  *(int4*)(off + gid*4)=v;
}

// ---------------------------------------------------------------- reorder (2-pass)
__global__ __launch_bounds__(256) void k_reorder1(const float* kt, int* off, int* srcIdx){
  int m = blockIdx.x*256+threadIdx.x;
  float kx=kt[2*m], ky=kt[2*m+1];
  int ix=((int)floorf(kx*1024.f))&1023;
  int iy=((int)floorf(ky*1024.f))&1023;
  int pos = atomicAdd(&off[(ix<<10)|iy],1);
  srcIdx[pos]=m;
}

__global__ __launch_bounds__(256) void k_reorder2(const int* srcIdx, const float* kt,
                                                  const float* kre, const float* kim,
                                                  float2* stat, int* cellArr,
                                                  float2* ysub, float2* kdat, const float* t){
  int p = blockIdx.x*256+threadIdx.x;
  int m = srcIdx[p];
  float kx=kt[2*m], ky=kt[2*m+1];
  float gx=kx*1024.f, gy=ky*1024.f;
  float fx=floorf(gx), fy=floorf(gy);
  float tx=gx-fx, ty=gy-fy;
  int ix=((int)fx)&1023, iy=((int)fy)&1023;
  stat[p]=make_float2(tx,ty);
  cellArr[p]=(ix<<10)|iy;
  float dx=kx-0.5f, dy=ky-0.5f;
  float r=sqrtf(dx*dx+dy*dy);
  float dcf=sqrtf(r/(t[15]+1e-8f));
  ysub[p]=make_float2(kre[m]*dcf, kim[m]*dcf);
  int idx[4]; float w[4];
  corners(kx,ky,idx,w);
  float s=0.f;
#pragma unroll
  for(int q=0;q<4;q++) if (idx[q]==0) s+=w[q];
  kdat[p]=make_float2(1024.f*s,0.f);
}

// ---------------------------------------------------------------- adjoint: one block per grid row, LDS accumulation
// Fuses the chain reduction (sum of part[] -> sc) when chain_n>0; writes t[chain_n-1].
__global__ __launch_bounds__(256) void k_adj(const float2* __restrict__ stat,
                                             const float2* __restrict__ kdat,
                                             const int* __restrict__ off,
                                             const int* __restrict__ cellArr,
                                             float2* __restrict__ G,
                                             float* t, const float* __restrict__ part,
                                             int chain_n){
  __shared__ float accx[1024], accy[1024];
  __shared__ float sm[4];
  __shared__ float scv;
  int r = blockIdx.x, tid=threadIdx.x;
  for(int k=tid;k<1024;k+=256){ accx[k]=0.f; accy[k]=0.f; }
  float sc=1.f;
  if (chain_n>0){
    float s=0.f;
    for(int k=tid;k<1024;k+=256) s+=part[k];
    for(int o=32;o>0;o>>=1) s+=__shfl_down(s,o,64);
    if((tid&63)==0) sm[tid>>6]=s;
    __syncthreads();
    if(tid==0){
      float dot=sm[0]+sm[1]+sm[2]+sm[3];
      float tv;
      if (chain_n==1) tv=dot;
      else {
        tv=t[0];
        for(int k=1;k<chain_n-1;k++) tv = t[k]/(sqrtf(tv)+1e-12f);
        tv = dot/(sqrtf(tv)+1e-12f);
      }
      scv = 1.f/(sqrtf(tv)+1e-12f);
      t[chain_n-1]=dot;           // same value from every block: benign
    }
    __syncthreads();
    sc=scv;
  }
  __syncthreads();   // acc zero + scv visible
  // side 0: points whose base row == r contribute with wx = 1-tx
  // side 1: points whose base row == r-1 contribute with wx = tx
#pragma unroll
  for(int side=0;side<2;side++){
    int br = side ? ((r-1)&1023) : r;
    int s0 = (br==0)? 0 : off[(br<<10)-1];
    int s1 = off[((br+1)<<10)-1];
    for(int j=s0+tid; j<s1; j+=256){
      float2 st=stat[j]; float2 v=kdat[j];
      int bc=cellArr[j]&1023, bc1=(bc+1)&1023;
      float wx = side ? st.x : 1.f-st.x;
      float w0 = wx*(1.f-st.y), w1 = wx*st.y;
      atomicAdd(&accx[bc],  w0*v.x); atomicAdd(&accy[bc],  w0*v.y);
      atomicAdd(&accx[bc1], w1*v.x); atomicAdd(&accy[bc1], w1*v.y);
    }
  }
  __syncthreads();
  float2* Grow = G + ((size_t)r<<10);
  for(int k=tid;k<1024;k+=256)
    Grow[k]=make_float2(accx[k]*sc, accy[k]*sc);
}

// ---------------------------------------------------------------- forward: one block per point-row, G rows staged in LDS
__global__ __launch_bounds__(256) void k_fwd_pow(const float2* __restrict__ G,
                                                 const int* __restrict__ cellArr,
                                                 const float2* __restrict__ stat,
                                                 const int* __restrict__ off,
                                                 float2* kdat, float* part, float* part2, int last){
  __shared__ float gx0[1024], gy0[1024], gx1[1024], gy1[1024];
  __shared__ float sm[4];
  int r=blockIdx.x, tid=threadIdx.x;
  const float2* Ga = G + ((size_t)r<<10);
  const float2* Gb = G + ((size_t)((r+1)&1023)<<10);
  for(int k=tid;k<1024;k+=256){
    float2 a=Ga[k]; gx0[k]=a.x; gy0[k]=a.y;
    float2 b=Gb[k]; gx1[k]=b.x; gy1[k]=b.y;
  }
  __syncthreads();
  int s0 = (r==0)? 0 : off[(r<<10)-1];
  int s1 = off[((r+1)<<10)-1];
  float dot=0.f, ssq=0.f;
  for(int j=s0+tid;j<s1;j+=256){
    float2 st=stat[j];
    int bc=cellArr[j]&1023, bc1=(bc+1)&1023;
    float tx=st.x, ty=st.y, ux=1.f-tx, uy=1.f-ty;
    float sx = ux*(uy*gx0[bc]+ty*gx0[bc1]) + tx*(uy*gx1[bc]+ty*gx1[bc1]);
    float sy = ux*(uy*gy0[bc]+ty*gy0[bc1]) + tx*(uy*gy1[bc]+ty*gy1[bc1]);
    float2 old=kdat[j];
    dot = fmaf(sx,old.x,fmaf(sy,old.y,dot));
    ssq = fmaf(sx,sx,fmaf(sy,sy,ssq));
    kdat[j]=make_float2(sx,sy);
  }
  for(int o=32;o>0;o>>=1) dot+=__shfl_down(dot,o,64);
  if((tid&63)==0) sm[tid>>6]=dot;
  __syncthreads();
  if(tid==0) part[r]=sm[0]+sm[1]+sm[2]+sm[3];
  if (last){
    __syncthreads();
    for(int o=32;o>0;o>>=1) ssq+=__shfl_down(ssq,o,64);
    if((tid&63)==0) sm[tid>>6]=ssq;
    __syncthreads();
    if(tid==0) part2[r]=sm[0]+sm[1]+sm[2]+sm[3];
  }
}

__global__ __launch_bounds__(256) void k_fwd_sub(const float2* __restrict__ G,
                                                 const int* __restrict__ cellArr,
                                                 const float2* __restrict__ stat,
                                                 const int* __restrict__ off,
                                                 const float2* __restrict__ ysub,
                                                 float2* kdat){
  __shared__ float gx0[1024], gy0[1024], gx1[1024], gy1[1024];
  int r=blockIdx.x, tid=threadIdx.x;
  const float2* Ga = G + ((size_t)r<<10);
  const float2* Gb = G + ((size_t)((r+1)&1023)<<10);
  for(int k=tid;k<1024;k+=256){
    float2 a=Ga[k]; gx0[k]=a.x; gy0[k]=a.y;
    float2 b=Gb[k]; gx1[k]=b.x; gy1[k]=b.y;
  }
  __syncthreads();
  int s0 = (r==0)? 0 : off[(r<<10)-1];
  int s1 = off[((r+1)<<10)-1];
  for(int j=s0+tid;j<s1;j+=256){
    float2 st=stat[j];
    int bc=cellArr[j]&1023, bc1=(bc+1)&1023;
    float tx=st.x, ty=st.y, ux=1.f-tx, uy=1.f-ty;
    float sx = ux*(uy*gx0[bc]+ty*gx0[bc1]) + tx*(uy*gx1[bc]+ty*gx1[bc1]);
    float sy = ux*(uy*gy0[bc]+ty*gy0[bc1]) + tx*(uy*gy1[bc]+ty*gy1[bc1]);
    float2 yv = ysub[j];
    kdat[j]=make_float2(sx-yv.x, sy-yv.y);
  }
}

// final reduce: t[8], t[10]=ssq, then w_reg -> t[19]
__global__ __launch_bounds__(256) void k_reduce_last(const float* part, const float* part2,
                                                     const float* wraw, float* t){
  int tid=threadIdx.x;
  float s1=0.f, s2=0.f;
  for(int k=tid;k<1024;k+=256){ s1+=part[k]; s2+=part2[k]; }
  __shared__ float sm[8];
  for(int o=32;o>0;o>>=1){ s1+=__shfl_down(s1,o,64); s2+=__shfl_down(s2,o,64); }
  if((tid&63)==0){ sm[tid>>6]=s1; sm[4+(tid>>6)]=s2; }
  __syncthreads();
  if(tid==0){
    float sum=sm[0]+sm[1]+sm[2]+sm[3];
    float ssq=sm[4]+sm[5]+sm[6]+sm[7];
    t[8]=sum; t[10]=ssq;
    float tv=t[0];
    for(int k=1;k<=8;k++){ float val=(k==8)? sum : t[k]; tv = val/(sqrtf(tv)+1e-12f); }
    float c9=1.f/(sqrtf(tv)+1e-12f);
    float avn=c9*sqrtf(ssq);
    float vn=sqrtf(tv)*c9;
    float opn=avn/(vn+1e-12f);
    float sig=1.f/(1.f+__expf(-wraw[0]));
    t[19]=2.f*sig/(opn*opn);
  }
}

// ---------------------------------------------------------------- composed-conv tables
// ec layout (floats): [0..99] E[oc*50+ic*25+dy*5+dx]; [100..101] C0;
// [102..119] Bb[oc*9+u]; [120..443] Btab[oc*162+u*18+ic*9+v]; [444..445] b2
__global__ __launch_bounds__(256) void k_mkE(const float* w1, const float* b1,
                                             const float* w2, const float* b2, float* ec){
  __shared__ float sw1[576], sw2[576], sb1[32], sB[324];
  int tid=threadIdx.x;
  for(int p=tid;p<576;p+=256){ sw1[p]=w1[p]; sw2[p]=w2[p]; }
  if(tid<32) sb1[tid]=b1[tid];
  __syncthreads();
  for(int e=tid;e<324;e+=256){
    int oc=e/162, r=e-oc*162, u=r/18, r2=r-u*18, ic=r2/9, v=r2-ic*9;
    float s=0.f;
    for(int cm=0;cm<32;cm++) s=fmaf(sw2[oc*288+cm*9+u], sw1[cm*18+ic*9+v], s);
    sB[e]=s; ec[120+e]=s;
  }
  if(tid<18){
    int oc=tid/9, u=tid-oc*9;
    float s=0.f;
    for(int cm=0;cm<32;cm++) s=fmaf(sw2[oc*288+cm*9+u], sb1[cm], s);
    ec[102+tid]=s;
  }
  if(tid<2){
    float s=b2[tid];
    for(int u=0;u<9;u++){
      float bb=0.f;
      for(int cm=0;cm<32;cm++) bb=fmaf(sw2[tid*288+cm*9+u], sb1[cm], bb);
      s+=bb;
    }
    ec[100+tid]=s;
    ec[444+tid]=b2[tid];
  }
  __syncthreads();
  if(tid<100){
    int oc=tid/50, r=tid-oc*50, ic=r/25, r2=r-ic*25, dy=r2/5, dx=r2-dy*5;
    float s=0.f;
    for(int uy=0;uy<3;uy++){ int vy=dy-uy; if(vy<0||vy>2) continue;
      for(int ux=0;ux<3;ux++){ int vx=dx-ux; if(vx<0||vx>2) continue;
        s+=sB[oc*162+(uy*3+ux)*18+ic*9+vy*3+vx];
      }
    }
    ec[tid]=s;
  }
}

// ---------------------------------------------------------------- fused 5x5 composed CNN + update
// blocks 0..1023: interior tiles (skip border pixels); blocks 1024..1039: border ring
#define CT_S 41
__global__ __launch_bounds__(256) void k_cnn5(const float2* __restrict__ x, const float2* __restrict__ res,
    const float* __restrict__ ec, const float* __restrict__ t,
    float2* __restrict__ xout, float* __restrict__ outPlanar){
  int tid=threadIdx.x;
  if (blockIdx.x>=1024){
    // ---- border ring: exact conv2(conv1) with h zero-masked outside image
    int id = (blockIdx.x-1024)*256+tid;   // 4096
    int py,px;
    if (id<1024){ py=0; px=id; }
    else if(id<2048){ py=1023; px=id-1024; }
    else if(id<3072){ py=id-2048; px=0; }
    else { py=id-3072; px=1023; }
    float s0=ec[444], s1=ec[445];
    for(int uy=0;uy<3;uy++){
      int qy=py+uy-1; if((unsigned)qy>=1024u) continue;
      for(int ux=0;ux<3;ux++){
        int qx=px+ux-1; if((unsigned)qx>=1024u) continue;
        int u=uy*3+ux;
        s0+=ec[102+u]; s1+=ec[111+u];
        const float* B0=&ec[120+u*18];
        const float* B1=&ec[282+u*18];
        for(int vy=0;vy<3;vy++){
          int sy2=qy+vy-1; if((unsigned)sy2>=1024u) continue;
          for(int vx=0;vx<3;vx++){
            int sx2=qx+vx-1; if((unsigned)sx2>=1024u) continue;
            int v=vy*3+vx;
            float2 xv=x[(size_t)sy2*W_+sx2];
            s0 = fmaf(B0[v],xv.x,fmaf(B0[9+v],xv.y,s0));
            s1 = fmaf(B1[v],xv.x,fmaf(B1[9+v],xv.y,s1));
          }
        }
      }
    }
    float wreg=t[19];
    size_t base=(size_t)py*W_+px;
    float2 xv=x[base], rv=res[base];
    float o0=xv.x - wreg*rv.x - s0;
    float o1=xv.y - wreg*rv.y - s1;
    if (outPlanar){ outPlanar[base]=o0; outPlanar[HW_+base]=o1; }
    else          { xout[base]=make_float2(o0,o1); }
    return;
  }
  __shared__ float xt0[36*CT_S];
  __shared__ float xt1[36*CT_S];
  __shared__ float sE[102];
  int by=blockIdx.x>>5, bx=blockIdx.x&31;
  int ty0=by<<5, tx0=bx<<5;
  for(int p=tid;p<102;p+=256) sE[p]=ec[p];
  for(int p=tid;p<1296;p+=256){
    int r=p/36, c=p-r*36;
    int gy=ty0-2+r, gx=tx0-2+c;
    float vx=0.f, vy=0.f;
    if((unsigned)gy<1024u && (unsigned)gx<1024u){ float2 v=x[(size_t)gy*W_+gx]; vx=v.x; vy=v.y; }
    xt0[r*CT_S+c]=vx; xt1[r*CT_S+c]=vy;
  }
  __syncthreads();
  int row=tid>>3, c4=(tid&7)<<2;
  float a0[4], a1[4];
  float C00=sE[100], C01=sE[101];
#pragma unroll
  for(int jj=0;jj<4;jj++){ a0[jj]=C00; a1[jj]=C01; }
#pragma unroll
  for(int dy=0;dy<5;dy++){
    const float* r0=&xt0[(row+dy)*CT_S+c4];
    const float* r1=&xt1[(row+dy)*CT_S+c4];
    float f0[9], f1[9];
#pragma unroll
    for(int q=0;q<9;q++){ f0[q]=r0[q]; f1[q]=r1[q]; }
#pragma unroll
    for(int dx=0;dx<5;dx++){
      float e00=sE[dy*5+dx], e01=sE[25+dy*5+dx];
      float e10=sE[50+dy*5+dx], e11=sE[75+dy*5+dx];
#pragma unroll
      for(int jj=0;jj<4;jj++){
        a0[jj]=fmaf(e00,f0[jj+dx],fmaf(e01,f1[jj+dx],a0[jj]));
        a1[jj]=fmaf(e10,f0[jj+dx],fmaf(e11,f1[jj+dx],a1[jj]));
      }
    }
  }
  int py=ty0+row;
  float wreg = t[19];
  size_t base=(size_t)py*W_ + tx0 + c4;
  bool rowEdge = (py==0)||(py==1023);
  if (outPlanar){
#pragma unroll
    for(int jj=0;jj<4;jj++){
      int px=tx0+c4+jj;
      if (rowEdge || px==0 || px==1023) continue;   // ring blocks own these
      float2 rv=res[base+jj];
      float xr_=xt0[(row+2)*CT_S+c4+jj+2];
      float xi_=xt1[(row+2)*CT_S+c4+jj+2];
      outPlanar[base+jj]      = xr_ - wreg*rv.x - a0[jj];
      outPlanar[HW_+base+jj]  = xi_ - wreg*rv.y - a1[jj];
    }
  } else {
#pragma unroll
    for(int jj=0;jj<4;jj++){
      int px=tx0+c4+jj;
      if (rowEdge || px==0 || px==1023) continue;
      float2 rv=res[base+jj];
      float xr_=xt0[(row+2)*CT_S+c4+jj+2];
      float xi_=xt1[(row+2)*CT_S+c4+jj+2];
      xout[base+jj]=make_float2(xr_ - wreg*rv.x - a0[jj],
                                xi_ - wreg*rv.y - a1[jj]);
    }
  }
}

// ================================================================ launch
extern "C" void kernel_launch(void* const* d_in, const int* in_sizes, int n_in,
                              void* d_out, int out_size, void* d_ws, size_t ws_size,
                              hipStream_t stream){
  (void)in_sizes; (void)n_in; (void)out_size; (void)ws_size;
  const float* xr  =(const float*)d_in[0];
  const float* xi  =(const float*)d_in[1];
  const float* kre =(const float*)d_in[2];
  const float* kim =(const float*)d_in[3];
  const float* kt  =(const float*)d_in[4];
  const float* wraw=(const float*)d_in[5];
  const float* w1  =(const float*)d_in[6];
  const float* b1  =(const float*)d_in[7];
  const float* w2  =(const float*)d_in[8];
  const float* b2  =(const float*)d_in[9];
  float* out = (float*)d_out;

  char* ws=(char*)d_ws;
  float2* Wx0 =(float2*)(ws);                      // 8MB
  float2* Wx1 =(float2*)(ws + ((size_t) 8<<20));   // 8MB
  int*   counts=(int*)   (ws + ((size_t) 8<<20));  // 4MB alias of Wx1 (setup only)
  int*   srcIdx=(int*)   (ws + ((size_t)12<<20));  // 2MB alias of Wx1 tail (setup only)
  float2* WF  =(float2*)(ws + ((size_t)16<<20));   // 8MB
  float2* kdat=(float2*)(ws + ((size_t)24<<20));   // 4MB
  float2* stat=(float2*)(ws + ((size_t)28<<20));   // 4MB
  float2* ysub=(float2*)(ws + ((size_t)32<<20));   // 4MB
  int*  cellA =(int*)   (ws + ((size_t)36<<20));   // 2MB
  int*  off   =(int*)   (ws + ((size_t)38<<20));   // 4MB
  int*  bsum  =(int*)   (ws + ((size_t)42<<20));   // 4KB
  float* t    =(float*) (ws + ((size_t)42<<20) + 8192);
  float* ec   =(float*) (ws + ((size_t)42<<20) + 16384);
  float* part =(float*) (ws + ((size_t)42<<20) + 32768);
  float* part2=(float*) (ws + ((size_t)42<<20) + 40960);
  float* pmax =(float*) (ws + ((size_t)42<<20) + 49152);
  const float SC = 0.03125f;   // 1/32 per 1-D ortho pass

  // ---- setup
  k_pack<<<HW_/256,256,0,stream>>>(xr,xi,Wx0,t);
  k_mkE<<<1,256,0,stream>>>(w1,b1,w2,b2,ec);
  hipMemsetAsync(counts,0,(size_t)HW_*sizeof(int),stream);
  k_hist<<<M_/256,256,0,stream>>>(kt,counts,pmax);
  k_reduce_max<<<1,256,0,stream>>>(pmax,t);
  k_scan1<<<1024,256,0,stream>>>(counts,off,bsum);
  k_scan2<<<1,256,0,stream>>>(bsum);
  k_scan3<<<1024,256,0,stream>>>(off,bsum);
  k_reorder1<<<M_/256,256,0,stream>>>(kt,off,srcIdx);
  k_reorder2<<<M_/256,256,0,stream>>>(srcIdx,kt,kre,kim,stat,cellA,ysub,kdat,t);

  // ---- power iteration, fully in k-space (fft2/ifft2 cancel; Parseval for norms)
  for (int n=0;n<9;n++){
    k_adj<<<1024,256,0,stream>>>(stat,kdat,off,cellA,WF,t,part,n);
    k_fwd_pow<<<1024,256,0,stream>>>(WF,cellA,stat,off,kdat,part,part2,(n==8)?1:0);
  }
  k_reduce_last<<<1,256,0,stream>>>(part,part2,wraw,t);

  // ---- npcg = 4 PGD iterations
  for (int it=0; it<4; it++){
    float2* xin  = (it&1)? Wx1 : Wx0;
    float2* xout = (it&1)? Wx0 : Wx1;
    float* planar = (it==3)? out : (float*)nullptr;
    k_fft_rows<-1><<<H_,256,0,stream>>>(xin,WF,SC);
    k_fft_cols<-1><<<W_/4,256,0,stream>>>(WF,SC);
    k_fwd_sub<<<1024,256,0,stream>>>(WF,cellA,stat,off,ysub,kdat);
    k_adj<<<1024,256,0,stream>>>(stat,kdat,off,cellA,WF,t,part,-1);
    k_fft_rows<1><<<H_,256,0,stream>>>(WF,WF,SC);
    k_fft_cols<1><<<W_/4,256,0,stream>>>(WF,SC);
    k_cnn5<<<1040,256,0,stream>>>(xin,WF,ec,t,xout,planar);
  }
}

// Round 7
// 734.976 us; speedup vs baseline: 1.1893x; 1.1893x over previous
//
#include <hip/hip_runtime.h>

#define H_  1024
#define W_  1024
#define HW_ (H_*W_)
#define M_  524288

#define SWZ(a) ((a) + ((a)>>4))

// ---------------------------------------------------------------- complex mul
__device__ __forceinline__ float2 cmulf(float2 a, float2 b){
  return make_float2(fmaf(a.x,b.x,-(a.y*b.y)), fmaf(a.x,b.y,a.y*b.x));
}

// ---------------------------------------------------------------- radix-4 bfly
template<int DIR>
__device__ __forceinline__ void bfly4(float2 v[4], int j, int Ns){
  if (Ns>1){
    float ang = ((DIR>0)?6.28318530717958647692f:-6.28318530717958647692f)
                * (float)(j&(Ns-1)) / (float)(4*Ns);
    float s,c; __sincosf(ang,&s,&c);
    float2 w1=make_float2(c,s);
    float2 w2=cmulf(w1,w1);
    float2 w3=cmulf(w2,w1);
    v[1]=cmulf(v[1],w1); v[2]=cmulf(v[2],w2); v[3]=cmulf(v[3],w3);
  }
  float2 t0=make_float2(v[0].x+v[2].x, v[0].y+v[2].y);
  float2 t2=make_float2(v[0].x-v[2].x, v[0].y-v[2].y);
  float2 t1=make_float2(v[1].x+v[3].x, v[1].y+v[3].y);
  float2 t3=make_float2(v[1].x-v[3].x, v[1].y-v[3].y);
  float2 t3r=(DIR<0)?make_float2(t3.y,-t3.x):make_float2(-t3.y,t3.x);
  v[0]=make_float2(t0.x+t1.x,  t0.y+t1.y);
  v[1]=make_float2(t2.x+t3r.x, t2.y+t3r.y);
  v[2]=make_float2(t0.x-t1.x,  t0.y-t1.y);
  v[3]=make_float2(t2.x-t3r.x, t2.y-t3r.y);
}

template<int DIR, int NS>
__device__ __forceinline__ void fft_stage(int j, const float2* src, float2* dst){
  float2 v[4];
#pragma unroll
  for(int r=0;r<4;r++) v[r]=src[SWZ(j+256*r)];
  bfly4<DIR>(v,j,NS);
  int base = ((j & ~(NS-1))<<2) | (j&(NS-1));
#pragma unroll
  for(int r=0;r<4;r++) dst[SWZ(base+NS*r)]=v[r];
}

template<int DIR>
__device__ __forceinline__ void fft1024_core(float2 v[4], int j, float2* A, float2* B, float scale){
  bfly4<DIR>(v,j,1);
#pragma unroll
  for(int r=0;r<4;r++) A[SWZ(4*j+r)]=v[r];
  __syncthreads();
  fft_stage<DIR,4 >(j,A,B); __syncthreads();
  fft_stage<DIR,16>(j,B,A); __syncthreads();
  fft_stage<DIR,64>(j,A,B); __syncthreads();
#pragma unroll
  for(int r=0;r<4;r++) v[r]=B[SWZ(j+256*r)];
  bfly4<DIR>(v,j,256);
#pragma unroll
  for(int r=0;r<4;r++){ v[r].x*=scale; v[r].y*=scale; }
}

template<int DIR>
__global__ __launch_bounds__(256) void k_fft_rows(const float2* src, float2* dst, float scale){
  __shared__ float2 A[1088], B[1088];
  int j = threadIdx.x;
  const float2* s = src + (size_t)blockIdx.x*W_;
  float2 v[4];
#pragma unroll
  for(int r=0;r<4;r++) v[r]=s[j+256*r];
  fft1024_core<DIR>(v,j,A,B,scale);
  float2* d = dst + (size_t)blockIdx.x*W_;
#pragma unroll
  for(int r=0;r<4;r++) d[j+256*r]=v[r];
}

template<int DIR>
__global__ __launch_bounds__(256) void k_fft_cols(float2* data, float scale){
  __shared__ float2 T[4*1025];
  __shared__ float2 A[1088], B[1088];
  int tid=threadIdx.x, c0=blockIdx.x*4;
#pragma unroll
  for(int k=0;k<16;k++){
    int idx=tid+256*k; int c=idx&3, r=idx>>2;
    T[c*1025+r]=data[(size_t)r*W_ + c0 + c];
  }
  __syncthreads();
  for(int c=0;c<4;c++){
    float2* col = T + c*1025;
    float2 v[4];
#pragma unroll
    for(int r=0;r<4;r++) v[r]=col[tid+256*r];
    fft1024_core<DIR>(v,tid,A,B,scale);
#pragma unroll
    for(int r=0;r<4;r++) col[tid+256*r]=v[r];
  }
  __syncthreads();
#pragma unroll
  for(int k=0;k<16;k++){
    int idx=tid+256*k; int c=idx&3, r=idx>>2;
    data[(size_t)r*W_ + c0 + c]=T[c*1025+r];
  }
}

// ---------------------------------------------------------------- interp helpers
__device__ __forceinline__ void corners(float kx, float ky, int idx[4], float w[4]){
  float gx = kx*1024.f, gy = ky*1024.f;
  float fx = floorf(gx), fy = floorf(gy);
  float tx = gx-fx, ty = gy-fy;
  int ix = ((int)fx)&1023, iy = ((int)fy)&1023;
  int ix1=(ix+1)&1023, iy1=(iy+1)&1023;
  idx[0]=(ix<<10)|iy;  idx[1]=(ix1<<10)|iy;
  idx[2]=(ix<<10)|iy1; idx[3]=(ix1<<10)|iy1;
  float ux=1.f-tx, uy=1.f-ty;
  w[0]=ux*uy; w[1]=tx*uy; w[2]=ux*ty; w[3]=tx*ty;
}

// ---------------------------------------------------------------- adjoint accumulation for one row-strip of 4 cells
// (R5-verified logic, factored so k_adj and k_adj_fft share it)
__device__ __forceinline__ void adj_cells4(const float2* __restrict__ stat,
                                           const float2* __restrict__ kdat,
                                           const int* __restrict__ off,
                                           int r, int c0,
                                           float axr[4], float ayr[4]){
#pragma unroll
  for(int q=0;q<4;q++){ axr[q]=0.f; ayr[q]=0.f; }
#pragma unroll
  for(int dr=0;dr<2;dr++){
    int br=(r-dr)&1023;
    int rowbase=br<<10;
    if (c0>0){
      int O[6];
#pragma unroll
      for(int q=0;q<6;q++) O[q]=off[rowbase+c0-2+q];
#pragma unroll
      for(int i=0;i<5;i++){
        for(int j=O[i]; j<O[i+1]; j++){
          float2 st=stat[j]; float2 v=kdat[j];
          float wx = dr ? st.x : 1.f-st.x;
          float w0 = wx*(1.f-st.y), w1 = wx*st.y;
          if (i>=1){ axr[i-1]=fmaf(w0,v.x,axr[i-1]); ayr[i-1]=fmaf(w0,v.y,ayr[i-1]); }
          if (i<=3){ axr[i]  =fmaf(w1,v.x,axr[i]);   ayr[i]  =fmaf(w1,v.y,ayr[i]); }
        }
      }
    } else {
      int bw = rowbase+1023;
      int sw = off[bw-1], ew=off[bw];
      for(int j=sw;j<ew;j++){
        float2 st=stat[j]; float2 v=kdat[j];
        float wx = dr ? st.x : 1.f-st.x;
        float w1 = wx*st.y;
        axr[0]=fmaf(w1,v.x,axr[0]); ayr[0]=fmaf(w1,v.y,ayr[0]);
      }
      int O[5];
      O[0] = (rowbase==0)? 0 : off[rowbase-1];
#pragma unroll
      for(int q=1;q<5;q++) O[q]=off[rowbase+q-1];
#pragma unroll
      for(int i=0;i<4;i++){
        for(int j=O[i]; j<O[i+1]; j++){
          float2 st=stat[j]; float2 v=kdat[j];
          float wx = dr ? st.x : 1.f-st.x;
          float w0 = wx*(1.f-st.y), w1 = wx*st.y;
          axr[i]=fmaf(w0,v.x,axr[i]); ayr[i]=fmaf(w0,v.y,ayr[i]);
          if (i<=2){ axr[i+1]=fmaf(w1,v.x,axr[i+1]); ayr[i+1]=fmaf(w1,v.y,ayr[i+1]); }
        }
      }
    }
  }
}

// ---------------------------------------------------------------- init
__global__ __launch_bounds__(256) void k_pack(const float* xr, const float* xi, float2* X, float* t){
  int i = blockIdx.x*256+threadIdx.x;
  if (i<HW_) X[i]=make_float2(xr[i],xi[i]);
  if (blockIdx.x==0 && threadIdx.x<32) t[threadIdx.x]=0.f;
}

__global__ __launch_bounds__(256) void k_hist(const float* kt, int* counts, float* pmax){
  int m = blockIdx.x*256+threadIdx.x;
  float r = 0.f;
  {
    float kx=kt[2*m], ky=kt[2*m+1];
    float dx=kx-0.5f, dy=ky-0.5f;
    r = sqrtf(dx*dx+dy*dy);
    int ix = ((int)floorf(kx*1024.f))&1023;
    int iy = ((int)floorf(ky*1024.f))&1023;
    atomicAdd(&counts[(ix<<10)|iy],1);
  }
  for(int o=32;o>0;o>>=1) r = fmaxf(r, __shfl_down(r,o,64));
  __shared__ float sm[4];
  if((threadIdx.x&63)==0) sm[threadIdx.x>>6]=r;
  __syncthreads();
  if(threadIdx.x==0)
    pmax[blockIdx.x] = fmaxf(fmaxf(sm[0],sm[1]),fmaxf(sm[2],sm[3]));
}

__global__ __launch_bounds__(256) void k_reduce_max(const float* pmax, float* t){
  int tid=threadIdx.x;
  float s=-1e30f;
  for(int k=tid;k<2048;k+=256) s=fmaxf(s,pmax[k]);
  __shared__ float sm[4];
  for(int o=32;o>0;o>>=1) s=fmaxf(s,__shfl_down(s,o,64));
  if((tid&63)==0) sm[tid>>6]=s;
  __syncthreads();
  if(tid==0) t[15]=fmaxf(fmaxf(sm[0],sm[1]),fmaxf(sm[2],sm[3]));
}

// ---------------------------------------------------------------- scan
__global__ __launch_bounds__(256) void k_scan1(const int* cnt, int* off, int* bsum){
  __shared__ int sm[256];
  int base = blockIdx.x*1024;
  int tid = threadIdx.x;
  int4 c = *(const int4*)(cnt + base + tid*4);
  int s = c.x+c.y+c.z+c.w;
  sm[tid]=s; __syncthreads();
  int v=s;
  for(int o=1;o<256;o<<=1){
    int u = (tid>=o)? sm[tid-o]:0;
    __syncthreads();
    v += u; sm[tid]=v;
    __syncthreads();
  }
  int excl = v - s;
  int4 o4;
  o4.x=excl; o4.y=excl+c.x; o4.z=excl+c.x+c.y; o4.w=excl+c.x+c.y+c.z;
  *(int4*)(off+base+tid*4)=o4;
  if (tid==255) bsum[blockIdx.x]=v;
}

__global__ __launch_bounds__(256) void k_scan2(int* bsum){
  __shared__ int sm[256];
  int tid=threadIdx.x;
  int4 c = *(const int4*)(bsum + tid*4);
  int s = c.x+c.y+c.z+c.w;
  sm[tid]=s; __syncthreads();
  int v=s;
  for(int o=1;o<256;o<<=1){
    int u = (tid>=o)? sm[tid-o]:0;
    __syncthreads();
    v += u; sm[tid]=v;
    __syncthreads();
  }
  int excl=v-s;
  int4 o4;
  o4.x=excl; o4.y=excl+c.x; o4.z=excl+c.x+c.y; o4.w=excl+c.x+c.y+c.z;
  *(int4*)(bsum+tid*4)=o4;
}

__global__ __launch_bounds__(256) void k_scan3(int* off, const int* bbase){
  int gid = blockIdx.x*256+threadIdx.x;
  int b = bbase[gid>>8];
  int4 v = *(int4*)(off + gid*4);
  v.x+=b; v.y+=b; v.z+=b; v.w+=b;
  *(int4*)(off + gid*4)=v;
}

// ---------------------------------------------------------------- reorder (2-pass)
__global__ __launch_bounds__(256) void k_reorder1(const float* kt, int* off, int* srcIdx){
  int m = blockIdx.x*256+threadIdx.x;
  float kx=kt[2*m], ky=kt[2*m+1];
  int ix=((int)floorf(kx*1024.f))&1023;
  int iy=((int)floorf(ky*1024.f))&1023;
  int pos = atomicAdd(&off[(ix<<10)|iy],1);
  srcIdx[pos]=m;
}

__global__ __launch_bounds__(256) void k_reorder2(const int* srcIdx, const float* kt,
                                                  const float* kre, const float* kim,
                                                  float2* stat, int* cellArr,
                                                  float2* ysub, float2* kdat, const float* t){
  int p = blockIdx.x*256+threadIdx.x;
  int m = srcIdx[p];
  float kx=kt[2*m], ky=kt[2*m+1];
  float gx=kx*1024.f, gy=ky*1024.f;
  float fx=floorf(gx), fy=floorf(gy);
  float tx=gx-fx, ty=gy-fy;
  int ix=((int)fx)&1023, iy=((int)fy)&1023;
  stat[p]=make_float2(tx,ty);
  cellArr[p]=(ix<<10)|iy;
  float dx=kx-0.5f, dy=ky-0.5f;
  float r=sqrtf(dx*dx+dy*dy);
  float dcf=sqrtf(r/(t[15]+1e-8f));
  ysub[p]=make_float2(kre[m]*dcf, kim[m]*dcf);
  int idx[4]; float w[4];
  corners(kx,ky,idx,w);
  float s=0.f;
#pragma unroll
  for(int q=0;q<4;q++) if (idx[q]==0) s+=w[q];
  kdat[p]=make_float2(1024.f*s,0.f);
}

// ---------------------------------------------------------------- adjoint (power phase): 4 cells/thread, flat grid
__global__ __launch_bounds__(256) void k_adj(const float2* __restrict__ stat,
                                             const float2* __restrict__ kdat,
                                             const int* __restrict__ off,
                                             float2* __restrict__ G,
                                             const float* __restrict__ t, int chain_n){
  int gid = blockIdx.x*256+threadIdx.x;
  int r  = gid>>8;
  int c0 = (gid&255)<<2;
  float sc = (chain_n>0)? t[20+chain_n] : 1.f;
  float axr[4], ayr[4];
  adj_cells4(stat,kdat,off,r,c0,axr,ayr);
  size_t base=((size_t)r<<10)+c0;
#pragma unroll
  for(int q=0;q<4;q++) G[base+q]=make_float2(axr[q]*sc, ayr[q]*sc);
}

// ---------------------------------------------------------------- adjoint + row-FFT fused (npcg phase): block = grid row
__global__ __launch_bounds__(256) void k_adj_fft(const float2* __restrict__ stat,
                                                 const float2* __restrict__ kdat,
                                                 const int* __restrict__ off,
                                                 float2* __restrict__ WF, float scale){
  __shared__ float2 X[1024];
  __shared__ float2 A[1088], B[1088];
  int r = blockIdx.x, tid=threadIdx.x;
  int c0 = tid<<2;
  float axr[4], ayr[4];
  adj_cells4(stat,kdat,off,r,c0,axr,ayr);
#pragma unroll
  for(int q=0;q<4;q++) X[c0+q]=make_float2(axr[q],ayr[q]);
  __syncthreads();
  float2 v[4];
#pragma unroll
  for(int rr=0;rr<4;rr++) v[rr]=X[tid+256*rr];
  fft1024_core<1>(v,tid,A,B,scale);
  float2* d = WF + ((size_t)r<<10);
#pragma unroll
  for(int rr=0;rr<4;rr++) d[tid+256*rr]=v[rr];
}

// ---------------------------------------------------------------- forward gather (sorted order)
__device__ __forceinline__ void fwd_point(const float2* __restrict__ G, int cellv, float2 st,
                                          float& sx, float& sy){
  int ix=cellv>>10, iy=cellv&1023;
  int ix1=(ix+1)&1023, iy1=(iy+1)&1023;
  float tx=st.x, ty=st.y, ux=1.f-tx, uy=1.f-ty;
  float2 g00=G[(ix<<10)|iy], g10=G[(ix1<<10)|iy], g01=G[(ix<<10)|iy1], g11=G[(ix1<<10)|iy1];
  float w0=ux*uy, w1=tx*uy, w2=ux*ty, w3=tx*ty;
  sx = fmaf(w0,g00.x,fmaf(w1,g10.x,fmaf(w2,g01.x,w3*g11.x)));
  sy = fmaf(w0,g00.y,fmaf(w1,g10.y,fmaf(w2,g01.y,w3*g11.y)));
}

__global__ __launch_bounds__(256) void k_fwd_pow(const float2* __restrict__ G,
                                                 const int* __restrict__ cellArr,
                                                 const float2* __restrict__ stat,
                                                 float2* kdat, float* part, float* part2, int last){
  int j = blockIdx.x*256+threadIdx.x;
  float dot, ssq;
  {
    float sx,sy;
    fwd_point(G,cellArr[j],stat[j],sx,sy);
    float2 old = kdat[j];
    dot = sx*old.x + sy*old.y;
    ssq = sx*sx + sy*sy;
    kdat[j]=make_float2(sx,sy);
  }
  __shared__ float sm[4];
  for(int o=32;o>0;o>>=1) dot += __shfl_down(dot,o,64);
  if((threadIdx.x&63)==0) sm[threadIdx.x>>6]=dot;
  __syncthreads();
  if(threadIdx.x==0) part[blockIdx.x]=sm[0]+sm[1]+sm[2]+sm[3];
  if (last){
    __syncthreads();
    for(int o=32;o>0;o>>=1) ssq += __shfl_down(ssq,o,64);
    if((threadIdx.x&63)==0) sm[threadIdx.x>>6]=ssq;
    __syncthreads();
    if(threadIdx.x==0) part2[blockIdx.x]=sm[0]+sm[1]+sm[2]+sm[3];
  }
}

__global__ __launch_bounds__(256) void k_reduce_chain(const float* part, float* t, int n){
  int tid=threadIdx.x;
  float s=0.f;
  for(int k=tid;k<2048;k+=256) s+=part[k];
  __shared__ float sm[4];
  for(int o=32;o>0;o>>=1) s+=__shfl_down(s,o,64);
  if((tid&63)==0) sm[tid>>6]=s;
  __syncthreads();
  if(tid==0){
    float sum=sm[0]+sm[1]+sm[2]+sm[3];
    t[n]=sum;
    float tv = (n==0)? sum : t[0];
    for(int k=1;k<=n;k++){ float val=(k==n)? sum : t[k]; tv = val/(sqrtf(tv)+1e-12f); }
    t[21+n] = 1.f/(sqrtf(tv)+1e-12f);
  }
}

__global__ __launch_bounds__(256) void k_reduce_last(const float* part, const float* part2,
                                                     const float* wraw, float* t){
  int tid=threadIdx.x;
  float s1=0.f, s2=0.f;
  for(int k=tid;k<2048;k+=256){ s1+=part[k]; s2+=part2[k]; }
  __shared__ float sm[8];
  for(int o=32;o>0;o>>=1){ s1+=__shfl_down(s1,o,64); s2+=__shfl_down(s2,o,64); }
  if((tid&63)==0){ sm[tid>>6]=s1; sm[4+(tid>>6)]=s2; }
  __syncthreads();
  if(tid==0){
    float sum=sm[0]+sm[1]+sm[2]+sm[3];
    float ssq=sm[4]+sm[5]+sm[6]+sm[7];
    t[8]=sum; t[10]=ssq;
    float tv=t[0];
    for(int k=1;k<=8;k++){ float val=(k==8)? sum : t[k]; tv = val/(sqrtf(tv)+1e-12f); }
    float c9=1.f/(sqrtf(tv)+1e-12f);
    float avn=c9*sqrtf(ssq);
    float vn=sqrtf(tv)*c9;
    float opn=avn/(vn+1e-12f);
    float sig=1.f/(1.f+__expf(-wraw[0]));
    t[19]=2.f*sig/(opn*opn);
  }
}

__global__ __launch_bounds__(256) void k_fwd_sub(const float2* __restrict__ G,
                                                 const int* __restrict__ cellArr,
                                                 const float2* __restrict__ stat,
                                                 const float2* __restrict__ ysub,
                                                 float2* kdat){
  int j = blockIdx.x*256+threadIdx.x;
  float sx,sy;
  fwd_point(G,cellArr[j],stat[j],sx,sy);
  float2 yv = ysub[j];
  kdat[j]=make_float2(sx-yv.x, sy-yv.y);
}

// ---------------------------------------------------------------- composed-conv tables
// ec layout (floats): [0..99] E[oc*50+ic*25+dy*5+dx]; [100..101] C0;
// [102..119] Bb[oc*9+u]; [120..443] Btab[oc*162+u*18+ic*9+v]; [444..445] b2
__global__ __launch_bounds__(256) void k_mkE(const float* w1, const float* b1,
                                             const float* w2, const float* b2, float* ec){
  __shared__ float sw1[576], sw2[576], sb1[32], sB[324];
  int tid=threadIdx.x;
  for(int p=tid;p<576;p+=256){ sw1[p]=w1[p]; sw2[p]=w2[p]; }
  if(tid<32) sb1[tid]=b1[tid];
  __syncthreads();
  for(int e=tid;e<324;e+=256){
    int oc=e/162, r=e-oc*162, u=r/18, r2=r-u*18, ic=r2/9, v=r2-ic*9;
    float s=0.f;
    for(int cm=0;cm<32;cm++) s=fmaf(sw2[oc*288+cm*9+u], sw1[cm*18+ic*9+v], s);
    sB[e]=s; ec[120+e]=s;
  }
  if(tid<18){
    int oc=tid/9, u=tid-oc*9;
    float s=0.f;
    for(int cm=0;cm<32;cm++) s=fmaf(sw2[oc*288+cm*9+u], sb1[cm], s);
    ec[102+tid]=s;
  }
  if(tid<2){
    float s=b2[tid];
    for(int u=0;u<9;u++){
      float bb=0.f;
      for(int cm=0;cm<32;cm++) bb=fmaf(sw2[tid*288+cm*9+u], sb1[cm], bb);
      s+=bb;
    }
    ec[100+tid]=s;
    ec[444+tid]=b2[tid];
  }
  __syncthreads();
  if(tid<100){
    int oc=tid/50, r=tid-oc*50, ic=r/25, r2=r-ic*25, dy=r2/5, dx=r2-dy*5;
    float s=0.f;
    for(int uy=0;uy<3;uy++){ int vy=dy-uy; if(vy<0||vy>2) continue;
      for(int ux=0;ux<3;ux++){ int vx=dx-ux; if(vx<0||vx>2) continue;
        s+=sB[oc*162+(uy*3+ux)*18+ic*9+vy*3+vx];
      }
    }
    ec[tid]=s;
  }
}

// ---------------------------------------------------------------- fused 5x5 composed CNN + update
// blocks 0..1023: interior tiles (skip border pixels); blocks 1024..1039: border ring
#define CT_S 41
__global__ __launch_bounds__(256) void k_cnn5(const float2* __restrict__ x, const float2* __restrict__ res,
    const float* __restrict__ ec, const float* __restrict__ t,
    float2* __restrict__ xout, float* __restrict__ outPlanar){
  int tid=threadIdx.x;
  if (blockIdx.x>=1024){
    // ---- border ring: exact conv2(conv1) with h zero-masked outside image
    int id = (blockIdx.x-1024)*256+tid;   // 4096
    int py,px;
    if (id<1024){ py=0; px=id; }
    else if(id<2048){ py=1023; px=id-1024; }
    else if(id<3072){ py=id-2048; px=0; }
    else { py=id-3072; px=1023; }
    float s0=ec[444], s1=ec[445];
    for(int uy=0;uy<3;uy++){
      int qy=py+uy-1; if((unsigned)qy>=1024u) continue;
      for(int ux=0;ux<3;ux++){
        int qx=px+ux-1; if((unsigned)qx>=1024u) continue;
        int u=uy*3+ux;
        s0+=ec[102+u]; s1+=ec[111+u];
        const float* B0=&ec[120+u*18];
        const float* B1=&ec[282+u*18];
        for(int vy=0;vy<3;vy++){
          int sy2=qy+vy-1; if((unsigned)sy2>=1024u) continue;
          for(int vx=0;vx<3;vx++){
            int sx2=qx+vx-1; if((unsigned)sx2>=1024u) continue;
            int v=vy*3+vx;
            float2 xv=x[(size_t)sy2*W_+sx2];
            s0 = fmaf(B0[v],xv.x,fmaf(B0[9+v],xv.y,s0));
            s1 = fmaf(B1[v],xv.x,fmaf(B1[9+v],xv.y,s1));
          }
        }
      }
    }
    float wreg=t[19];
    size_t base=(size_t)py*W_+px;
    float2 xv=x[base], rv=res[base];
    float o0=xv.x - wreg*rv.x - s0;
    float o1=xv.y - wreg*rv.y - s1;
    if (outPlanar){ outPlanar[base]=o0; outPlanar[HW_+base]=o1; }
    else          { xout[base]=make_float2(o0,o1); }
    return;
  }
  __shared__ float xt0[36*CT_S];
  __shared__ float xt1[36*CT_S];
  __shared__ float sE[102];
  int by=blockIdx.x>>5, bx=blockIdx.x&31;
  int ty0=by<<5, tx0=bx<<5;
  for(int p=tid;p<102;p+=256) sE[p]=ec[p];
  for(int p=tid;p<1296;p+=256){
    int r=p/36, c=p-r*36;
    int gy=ty0-2+r, gx=tx0-2+c;
    float vx=0.f, vy=0.f;
    if((unsigned)gy<1024u && (unsigned)gx<1024u){ float2 v=x[(size_t)gy*W_+gx]; vx=v.x; vy=v.y; }
    xt0[r*CT_S+c]=vx; xt1[r*CT_S+c]=vy;
  }
  __syncthreads();
  int row=tid>>3, c4=(tid&7)<<2;
  float a0[4], a1[4];
  float C00=sE[100], C01=sE[101];
#pragma unroll
  for(int jj=0;jj<4;jj++){ a0[jj]=C00; a1[jj]=C01; }
#pragma unroll
  for(int dy=0;dy<5;dy++){
    const float* r0=&xt0[(row+dy)*CT_S+c4];
    const float* r1=&xt1[(row+dy)*CT_S+c4];
    float f0[9], f1[9];
#pragma unroll
    for(int q=0;q<9;q++){ f0[q]=r0[q]; f1[q]=r1[q]; }
#pragma unroll
    for(int dx=0;dx<5;dx++){
      float e00=sE[dy*5+dx], e01=sE[25+dy*5+dx];
      float e10=sE[50+dy*5+dx], e11=sE[75+dy*5+dx];
#pragma unroll
      for(int jj=0;jj<4;jj++){
        a0[jj]=fmaf(e00,f0[jj+dx],fmaf(e01,f1[jj+dx],a0[jj]));
        a1[jj]=fmaf(e10,f0[jj+dx],fmaf(e11,f1[jj+dx],a1[jj]));
      }
    }
  }
  int py=ty0+row;
  float wreg = t[19];
  size_t base=(size_t)py*W_ + tx0 + c4;
  bool rowEdge = (py==0)||(py==1023);
  if (outPlanar){
#pragma unroll
    for(int jj=0;jj<4;jj++){
      int px=tx0+c4+jj;
      if (rowEdge || px==0 || px==1023) continue;   // ring blocks own these
      float2 rv=res[base+jj];
      float xr_=xt0[(row+2)*CT_S+c4+jj+2];
      float xi_=xt1[(row+2)*CT_S+c4+jj+2];
      outPlanar[base+jj]      = xr_ - wreg*rv.x - a0[jj];
      outPlanar[HW_+base+jj]  = xi_ - wreg*rv.y - a1[jj];
    }
  } else {
#pragma unroll
    for(int jj=0;jj<4;jj++){
      int px=tx0+c4+jj;
      if (rowEdge || px==0 || px==1023) continue;
      float2 rv=res[base+jj];
      float xr_=xt0[(row+2)*CT_S+c4+jj+2];
      float xi_=xt1[(row+2)*CT_S+c4+jj+2];
      xout[base+jj]=make_float2(xr_ - wreg*rv.x - a0[jj],
                                xi_ - wreg*rv.y - a1[jj]);
    }
  }
}

// ================================================================ launch
extern "C" void kernel_launch(void* const* d_in, const int* in_sizes, int n_in,
                              void* d_out, int out_size, void* d_ws, size_t ws_size,
                              hipStream_t stream){
  (void)in_sizes; (void)n_in; (void)out_size; (void)ws_size;
  const float* xr  =(const float*)d_in[0];
  const float* xi  =(const float*)d_in[1];
  const float* kre =(const float*)d_in[2];
  const float* kim =(const float*)d_in[3];
  const float* kt  =(const float*)d_in[4];
  const float* wraw=(const float*)d_in[5];
  const float* w1  =(const float*)d_in[6];
  const float* b1  =(const float*)d_in[7];
  const float* w2  =(const float*)d_in[8];
  const float* b2  =(const float*)d_in[9];
  float* out = (float*)d_out;

  char* ws=(char*)d_ws;
  float2* Wx0 =(float2*)(ws);                      // 8MB
  float2* Wx1 =(float2*)(ws + ((size_t) 8<<20));   // 8MB
  int*   counts=(int*)   (ws + ((size_t) 8<<20));  // 4MB alias of Wx1 (setup only)
  int*   srcIdx=(int*)   (ws + ((size_t)12<<20));  // 2MB alias of Wx1 tail (setup only)
  float2* WF  =(float2*)(ws + ((size_t)16<<20));   // 8MB
  float2* kdat=(float2*)(ws + ((size_t)24<<20));   // 4MB
  float2* stat=(float2*)(ws + ((size_t)28<<20));   // 4MB
  float2* ysub=(float2*)(ws + ((size_t)32<<20));   // 4MB
  int*  cellA =(int*)   (ws + ((size_t)36<<20));   // 2MB
  int*  off   =(int*)   (ws + ((size_t)38<<20));   // 4MB
  int*  bsum  =(int*)   (ws + ((size_t)42<<20));   // 4KB
  float* t    =(float*) (ws + ((size_t)42<<20) + 8192);
  float* ec   =(float*) (ws + ((size_t)42<<20) + 16384);
  float* part =(float*) (ws + ((size_t)42<<20) + 32768);
  float* part2=(float*) (ws + ((size_t)42<<20) + 40960);
  float* pmax =(float*) (ws + ((size_t)42<<20) + 49152);
  const float SC = 0.03125f;   // 1/32 per 1-D ortho pass

  // ---- setup
  k_pack<<<HW_/256,256,0,stream>>>(xr,xi,Wx0,t);
  k_mkE<<<1,256,0,stream>>>(w1,b1,w2,b2,ec);
  hipMemsetAsync(counts,0,(size_t)HW_*sizeof(int),stream);
  k_hist<<<M_/256,256,0,stream>>>(kt,counts,pmax);
  k_reduce_max<<<1,256,0,stream>>>(pmax,t);
  k_scan1<<<1024,256,0,stream>>>(counts,off,bsum);
  k_scan2<<<1,256,0,stream>>>(bsum);
  k_scan3<<<1024,256,0,stream>>>(off,bsum);
  k_reorder1<<<M_/256,256,0,stream>>>(kt,off,srcIdx);
  k_reorder2<<<M_/256,256,0,stream>>>(srcIdx,kt,kre,kim,stat,cellA,ysub,kdat,t);

  // ---- power iteration, fully in k-space (fft2/ifft2 cancel; Parseval for norms)
  for (int n=0;n<9;n++){
    k_adj<<<HW_/1024,256,0,stream>>>(stat,kdat,off,WF,t,n);
    k_fwd_pow<<<M_/256,256,0,stream>>>(WF,cellA,stat,kdat,part,part2,(n==8)?1:0);
    if (n<8) k_reduce_chain<<<1,256,0,stream>>>(part,t,n);
    else     k_reduce_last <<<1,256,0,stream>>>(part,part2,wraw,t);
  }

  // ---- npcg = 4 PGD iterations
  for (int it=0; it<4; it++){
    float2* xin  = (it&1)? Wx1 : Wx0;
    float2* xout = (it&1)? Wx0 : Wx1;
    float* planar = (it==3)? out : (float*)nullptr;
    k_fft_rows<-1><<<H_,256,0,stream>>>(xin,WF,SC);
    k_fft_cols<-1><<<W_/4,256,0,stream>>>(WF,SC);
    k_fwd_sub<<<M_/256,256,0,stream>>>(WF,cellA,stat,ysub,kdat);
    k_adj_fft<<<H_,256,0,stream>>>(stat,kdat,off,WF,SC);
    k_fft_cols<1><<<W_/4,256,0,stream>>>(WF,SC);
    k_cnn5<<<1040,256,0,stream>>>(xin,WF,ec,t,xout,planar);
  }
}

// Round 8
// 725.212 us; speedup vs baseline: 1.2053x; 1.0135x over previous
//
#include <hip/hip_runtime.h>

#define H_  1024
#define W_  1024
#define HW_ (H_*W_)
#define M_  524288

#define SWZ(a) ((a) + ((a)>>4))

// ---------------------------------------------------------------- complex mul
__device__ __forceinline__ float2 cmulf(float2 a, float2 b){
  return make_float2(fmaf(a.x,b.x,-(a.y*b.y)), fmaf(a.x,b.y,a.y*b.x));
}

// ---------------------------------------------------------------- radix-4 bfly
template<int DIR>
__device__ __forceinline__ void bfly4(float2 v[4], int j, int Ns){
  if (Ns>1){
    float ang = ((DIR>0)?6.28318530717958647692f:-6.28318530717958647692f)
                * (float)(j&(Ns-1)) / (float)(4*Ns);
    float s,c; __sincosf(ang,&s,&c);
    float2 w1=make_float2(c,s);
    float2 w2=cmulf(w1,w1);
    float2 w3=cmulf(w2,w1);
    v[1]=cmulf(v[1],w1); v[2]=cmulf(v[2],w2); v[3]=cmulf(v[3],w3);
  }
  float2 t0=make_float2(v[0].x+v[2].x, v[0].y+v[2].y);
  float2 t2=make_float2(v[0].x-v[2].x, v[0].y-v[2].y);
  float2 t1=make_float2(v[1].x+v[3].x, v[1].y+v[3].y);
  float2 t3=make_float2(v[1].x-v[3].x, v[1].y-v[3].y);
  float2 t3r=(DIR<0)?make_float2(t3.y,-t3.x):make_float2(-t3.y,t3.x);
  v[0]=make_float2(t0.x+t1.x,  t0.y+t1.y);
  v[1]=make_float2(t2.x+t3r.x, t2.y+t3r.y);
  v[2]=make_float2(t0.x-t1.x,  t0.y-t1.y);
  v[3]=make_float2(t2.x-t3r.x, t2.y-t3r.y);
}

template<int DIR, int NS>
__device__ __forceinline__ void fft_stage(int j, const float2* src, float2* dst){
  float2 v[4];
#pragma unroll
  for(int r=0;r<4;r++) v[r]=src[SWZ(j+256*r)];
  bfly4<DIR>(v,j,NS);
  int base = ((j & ~(NS-1))<<2) | (j&(NS-1));
#pragma unroll
  for(int r=0;r<4;r++) dst[SWZ(base+NS*r)]=v[r];
}

template<int DIR>
__device__ __forceinline__ void fft1024_core(float2 v[4], int j, float2* A, float2* B, float scale){
  bfly4<DIR>(v,j,1);
#pragma unroll
  for(int r=0;r<4;r++) A[SWZ(4*j+r)]=v[r];
  __syncthreads();
  fft_stage<DIR,4 >(j,A,B); __syncthreads();
  fft_stage<DIR,16>(j,B,A); __syncthreads();
  fft_stage<DIR,64>(j,A,B); __syncthreads();
#pragma unroll
  for(int r=0;r<4;r++) v[r]=B[SWZ(j+256*r)];
  bfly4<DIR>(v,j,256);
#pragma unroll
  for(int r=0;r<4;r++){ v[r].x*=scale; v[r].y*=scale; }
}

template<int DIR>
__global__ __launch_bounds__(256) void k_fft_rows(const float2* src, float2* dst, float scale){
  __shared__ float2 A[1088], B[1088];
  int j = threadIdx.x;
  const float2* s = src + (size_t)blockIdx.x*W_;
  float2 v[4];
#pragma unroll
  for(int r=0;r<4;r++) v[r]=s[j+256*r];
  fft1024_core<DIR>(v,j,A,B,scale);
  float2* d = dst + (size_t)blockIdx.x*W_;
#pragma unroll
  for(int r=0;r<4;r++) d[j+256*r]=v[r];
}

template<int DIR>
__global__ __launch_bounds__(256) void k_fft_cols(float2* data, float scale){
  __shared__ float2 T[4*1025];
  __shared__ float2 A[1088], B[1088];
  int tid=threadIdx.x, c0=blockIdx.x*4;
#pragma unroll
  for(int k=0;k<16;k++){
    int idx=tid+256*k; int c=idx&3, r=idx>>2;
    T[c*1025+r]=data[(size_t)r*W_ + c0 + c];
  }
  __syncthreads();
  for(int c=0;c<4;c++){
    float2* col = T + c*1025;
    float2 v[4];
#pragma unroll
    for(int r=0;r<4;r++) v[r]=col[tid+256*r];
    fft1024_core<DIR>(v,tid,A,B,scale);
#pragma unroll
    for(int r=0;r<4;r++) col[tid+256*r]=v[r];
  }
  __syncthreads();
#pragma unroll
  for(int k=0;k<16;k++){
    int idx=tid+256*k; int c=idx&3, r=idx>>2;
    data[(size_t)r*W_ + c0 + c]=T[c*1025+r];
  }
}

// ---------------------------------------------------------------- interp helpers
__device__ __forceinline__ void corners(float kx, float ky, int idx[4], float w[4]){
  float gx = kx*1024.f, gy = ky*1024.f;
  float fx = floorf(gx), fy = floorf(gy);
  float tx = gx-fx, ty = gy-fy;
  int ix = ((int)fx)&1023, iy = ((int)fy)&1023;
  int ix1=(ix+1)&1023, iy1=(iy+1)&1023;
  idx[0]=(ix<<10)|iy;  idx[1]=(ix1<<10)|iy;
  idx[2]=(ix<<10)|iy1; idx[3]=(ix1<<10)|iy1;
  float ux=1.f-tx, uy=1.f-ty;
  w[0]=ux*uy; w[1]=tx*uy; w[2]=ux*ty; w[3]=tx*ty;
}

// ---------------------------------------------------------------- adjoint accumulation for one row-strip of 4 cells
// pd[j] = (tx, ty, vx, vy) -- single 16B load per point (latency-chain critical)
__device__ __forceinline__ void adj_cells4(const float4* __restrict__ pd,
                                           const int* __restrict__ off,
                                           int r, int c0,
                                           float axr[4], float ayr[4]){
#pragma unroll
  for(int q=0;q<4;q++){ axr[q]=0.f; ayr[q]=0.f; }
#pragma unroll
  for(int dr=0;dr<2;dr++){
    int br=(r-dr)&1023;
    int rowbase=br<<10;
    if (c0>0){
      int O[6];
#pragma unroll
      for(int q=0;q<6;q++) O[q]=off[rowbase+c0-2+q];
#pragma unroll
      for(int i=0;i<5;i++){
        for(int j=O[i]; j<O[i+1]; j++){
          float4 p=pd[j];
          float wx = dr ? p.x : 1.f-p.x;
          float w0 = wx*(1.f-p.y), w1 = wx*p.y;
          if (i>=1){ axr[i-1]=fmaf(w0,p.z,axr[i-1]); ayr[i-1]=fmaf(w0,p.w,ayr[i-1]); }
          if (i<=3){ axr[i]  =fmaf(w1,p.z,axr[i]);   ayr[i]  =fmaf(w1,p.w,ayr[i]); }
        }
      }
    } else {
      int bw = rowbase+1023;
      int sw = off[bw-1], ew=off[bw];
      for(int j=sw;j<ew;j++){
        float4 p=pd[j];
        float wx = dr ? p.x : 1.f-p.x;
        float w1 = wx*p.y;
        axr[0]=fmaf(w1,p.z,axr[0]); ayr[0]=fmaf(w1,p.w,ayr[0]);
      }
      int O[5];
      O[0] = (rowbase==0)? 0 : off[rowbase-1];
#pragma unroll
      for(int q=1;q<5;q++) O[q]=off[rowbase+q-1];
#pragma unroll
      for(int i=0;i<4;i++){
        for(int j=O[i]; j<O[i+1]; j++){
          float4 p=pd[j];
          float wx = dr ? p.x : 1.f-p.x;
          float w0 = wx*(1.f-p.y), w1 = wx*p.y;
          axr[i]=fmaf(w0,p.z,axr[i]); ayr[i]=fmaf(w0,p.w,ayr[i]);
          if (i<=2){ axr[i+1]=fmaf(w1,p.z,axr[i+1]); ayr[i+1]=fmaf(w1,p.w,ayr[i+1]); }
        }
      }
    }
  }
}

// ---------------------------------------------------------------- init
__global__ __launch_bounds__(256) void k_pack(const float* xr, const float* xi, float2* X, float* t){
  int i = blockIdx.x*256+threadIdx.x;
  if (i<HW_) X[i]=make_float2(xr[i],xi[i]);
  if (blockIdx.x==0 && threadIdx.x<32) t[threadIdx.x]=0.f;
}

__global__ __launch_bounds__(256) void k_hist(const float* kt, int* counts, float* pmax){
  int m = blockIdx.x*256+threadIdx.x;
  float r = 0.f;
  {
    float kx=kt[2*m], ky=kt[2*m+1];
    float dx=kx-0.5f, dy=ky-0.5f;
    r = sqrtf(dx*dx+dy*dy);
    int ix = ((int)floorf(kx*1024.f))&1023;
    int iy = ((int)floorf(ky*1024.f))&1023;
    atomicAdd(&counts[(ix<<10)|iy],1);
  }
  for(int o=32;o>0;o>>=1) r = fmaxf(r, __shfl_down(r,o,64));
  __shared__ float sm[4];
  if((threadIdx.x&63)==0) sm[threadIdx.x>>6]=r;
  __syncthreads();
  if(threadIdx.x==0)
    pmax[blockIdx.x] = fmaxf(fmaxf(sm[0],sm[1]),fmaxf(sm[2],sm[3]));
}

__global__ __launch_bounds__(256) void k_reduce_max(const float* pmax, float* t){
  int tid=threadIdx.x;
  float s=-1e30f;
  for(int k=tid;k<2048;k+=256) s=fmaxf(s,pmax[k]);
  __shared__ float sm[4];
  for(int o=32;o>0;o>>=1) s=fmaxf(s,__shfl_down(s,o,64));
  if((tid&63)==0) sm[tid>>6]=s;
  __syncthreads();
  if(tid==0) t[15]=fmaxf(fmaxf(sm[0],sm[1]),fmaxf(sm[2],sm[3]));
}

// ---------------------------------------------------------------- scan
__global__ __launch_bounds__(256) void k_scan1(const int* cnt, int* off, int* bsum){
  __shared__ int sm[256];
  int base = blockIdx.x*1024;
  int tid = threadIdx.x;
  int4 c = *(const int4*)(cnt + base + tid*4);
  int s = c.x+c.y+c.z+c.w;
  sm[tid]=s; __syncthreads();
  int v=s;
  for(int o=1;o<256;o<<=1){
    int u = (tid>=o)? sm[tid-o]:0;
    __syncthreads();
    v += u; sm[tid]=v;
    __syncthreads();
  }
  int excl = v - s;
  int4 o4;
  o4.x=excl; o4.y=excl+c.x; o4.z=excl+c.x+c.y; o4.w=excl+c.x+c.y+c.z;
  *(int4*)(off+base+tid*4)=o4;
  if (tid==255) bsum[blockIdx.x]=v;
}

__global__ __launch_bounds__(256) void k_scan2(int* bsum){
  __shared__ int sm[256];
  int tid=threadIdx.x;
  int4 c = *(const int4*)(bsum + tid*4);
  int s = c.x+c.y+c.z+c.w;
  sm[tid]=s; __syncthreads();
  int v=s;
  for(int o=1;o<256;o<<=1){
    int u = (tid>=o)? sm[tid-o]:0;
    __syncthreads();
    v += u; sm[tid]=v;
    __syncthreads();
  }
  int excl=v-s;
  int4 o4;
  o4.x=excl; o4.y=excl+c.x; o4.z=excl+c.x+c.y; o4.w=excl+c.x+c.y+c.z;
  *(int4*)(bsum+tid*4)=o4;
}

__global__ __launch_bounds__(256) void k_scan3(int* off, const int* bbase){
  int gid = blockIdx.x*256+threadIdx.x;
  int b = bbase[gid>>8];
  int4 v = *(int4*)(off + gid*4);
  v.x+=b; v.y+=b; v.z+=b; v.w+=b;
  *(int4*)(off + gid*4)=v;
}

// ---------------------------------------------------------------- reorder (2-pass)
__global__ __launch_bounds__(256) void k_reorder1(const float* kt, int* off, int* srcIdx){
  int m = blockIdx.x*256+threadIdx.x;
  float kx=kt[2*m], ky=kt[2*m+1];
  int ix=((int)floorf(kx*1024.f))&1023;
  int iy=((int)floorf(ky*1024.f))&1023;
  int pos = atomicAdd(&off[(ix<<10)|iy],1);
  srcIdx[pos]=m;
}

__global__ __launch_bounds__(256) void k_reorder2(const int* srcIdx, const float* kt,
                                                  const float* kre, const float* kim,
                                                  float4* pd, int* cellArr,
                                                  float2* ysub, const float* t){
  int p = blockIdx.x*256+threadIdx.x;
  int m = srcIdx[p];
  float kx=kt[2*m], ky=kt[2*m+1];
  float gx=kx*1024.f, gy=ky*1024.f;
  float fx=floorf(gx), fy=floorf(gy);
  float tx=gx-fx, ty=gy-fy;
  int ix=((int)fx)&1023, iy=((int)fy)&1023;
  cellArr[p]=(ix<<10)|iy;
  float dx=kx-0.5f, dy=ky-0.5f;
  float r=sqrtf(dx*dx+dy*dy);
  float dcf=sqrtf(r/(t[15]+1e-8f));
  ysub[p]=make_float2(kre[m]*dcf, kim[m]*dcf);
  // av0 = gather(fft2(ones)): weights whose target cell is (0,0)
  int idx[4]; float w[4];
  corners(kx,ky,idx,w);
  float s=0.f;
#pragma unroll
  for(int q=0;q<4;q++) if (idx[q]==0) s+=w[q];
  pd[p]=make_float4(tx,ty,1024.f*s,0.f);
}

// ---------------------------------------------------------------- adjoint (power phase): flat grid, 4 cells/thread,
// chain-reduce folded in (each block redundantly sums part[2048] -> sc; block 0 persists t[chain_n-1])
__global__ __launch_bounds__(256) void k_adj(const float4* __restrict__ pd,
                                             const int* __restrict__ off,
                                             float2* __restrict__ G,
                                             float* t, const float* __restrict__ part,
                                             int chain_n){
  __shared__ float sm[4];
  __shared__ float scv;
  int tid=threadIdx.x;
  float sc=1.f;
  if (chain_n>0){
    float s=0.f;
    for(int k=tid;k<2048;k+=256) s+=part[k];
    for(int o=32;o>0;o>>=1) s+=__shfl_down(s,o,64);
    if((tid&63)==0) sm[tid>>6]=s;
    __syncthreads();
    if(tid==0){
      float dot=sm[0]+sm[1]+sm[2]+sm[3];
      float tv;
      if (chain_n==1) tv=dot;
      else {
        tv=t[0];
        for(int k=1;k<chain_n-1;k++) tv = t[k]/(sqrtf(tv)+1e-12f);
        tv = dot/(sqrtf(tv)+1e-12f);
      }
      scv = 1.f/(sqrtf(tv)+1e-12f);
      if (blockIdx.x==0) t[chain_n-1]=dot;
    }
    __syncthreads();
    sc=scv;
  }
  int gid = blockIdx.x*256+tid;
  int r  = gid>>8;
  int c0 = (gid&255)<<2;
  float axr[4], ayr[4];
  adj_cells4(pd,off,r,c0,axr,ayr);
  size_t base=((size_t)r<<10)+c0;
#pragma unroll
  for(int q=0;q<4;q++) G[base+q]=make_float2(axr[q]*sc, ayr[q]*sc);
}

// ---------------------------------------------------------------- adjoint + row-FFT fused (npcg phase): block = grid row
__global__ __launch_bounds__(256) void k_adj_fft(const float4* __restrict__ pd,
                                                 const int* __restrict__ off,
                                                 float2* __restrict__ WF, float scale){
  __shared__ float2 X[1024];
  __shared__ float2 A[1088], B[1088];
  int r = blockIdx.x, tid=threadIdx.x;
  int c0 = tid<<2;
  float axr[4], ayr[4];
  adj_cells4(pd,off,r,c0,axr,ayr);
#pragma unroll
  for(int q=0;q<4;q++) X[c0+q]=make_float2(axr[q],ayr[q]);
  __syncthreads();
  float2 v[4];
#pragma unroll
  for(int rr=0;rr<4;rr++) v[rr]=X[tid+256*rr];
  fft1024_core<1>(v,tid,A,B,scale);
  float2* d = WF + ((size_t)r<<10);
#pragma unroll
  for(int rr=0;rr<4;rr++) d[tid+256*rr]=v[rr];
}

// ---------------------------------------------------------------- forward gather (sorted order)
__device__ __forceinline__ void fwd_point(const float2* __restrict__ G, int cellv, float tx, float ty,
                                          float& sx, float& sy){
  int ix=cellv>>10, iy=cellv&1023;
  int ix1=(ix+1)&1023, iy1=(iy+1)&1023;
  float ux=1.f-tx, uy=1.f-ty;
  float2 g00=G[(ix<<10)|iy], g10=G[(ix1<<10)|iy], g01=G[(ix<<10)|iy1], g11=G[(ix1<<10)|iy1];
  float w0=ux*uy, w1=tx*uy, w2=ux*ty, w3=tx*ty;
  sx = fmaf(w0,g00.x,fmaf(w1,g10.x,fmaf(w2,g01.x,w3*g11.x)));
  sy = fmaf(w0,g00.y,fmaf(w1,g10.y,fmaf(w2,g01.y,w3*g11.y)));
}

__global__ __launch_bounds__(256) void k_fwd_pow(const float2* __restrict__ G,
                                                 const int* __restrict__ cellArr,
                                                 float4* pd, float* part, float* part2, int last){
  int j = blockIdx.x*256+threadIdx.x;
  float dot, ssq;
  {
    float4 p = pd[j];
    float sx,sy;
    fwd_point(G,cellArr[j],p.x,p.y,sx,sy);
    dot = sx*p.z + sy*p.w;
    ssq = sx*sx + sy*sy;
    pd[j]=make_float4(p.x,p.y,sx,sy);
  }
  __shared__ float sm[4];
  for(int o=32;o>0;o>>=1) dot += __shfl_down(dot,o,64);
  if((threadIdx.x&63)==0) sm[threadIdx.x>>6]=dot;
  __syncthreads();
  if(threadIdx.x==0) part[blockIdx.x]=sm[0]+sm[1]+sm[2]+sm[3];
  if (last){
    __syncthreads();
    for(int o=32;o>0;o>>=1) ssq += __shfl_down(ssq,o,64);
    if((threadIdx.x&63)==0) sm[threadIdx.x>>6]=ssq;
    __syncthreads();
    if(threadIdx.x==0) part2[blockIdx.x]=sm[0]+sm[1]+sm[2]+sm[3];
  }
}

__global__ __launch_bounds__(256) void k_reduce_last(const float* part, const float* part2,
                                                     const float* wraw, float* t){
  int tid=threadIdx.x;
  float s1=0.f, s2=0.f;
  for(int k=tid;k<2048;k+=256){ s1+=part[k]; s2+=part2[k]; }
  __shared__ float sm[8];
  for(int o=32;o>0;o>>=1){ s1+=__shfl_down(s1,o,64); s2+=__shfl_down(s2,o,64); }
  if((tid&63)==0){ sm[tid>>6]=s1; sm[4+(tid>>6)]=s2; }
  __syncthreads();
  if(tid==0){
    float sum=sm[0]+sm[1]+sm[2]+sm[3];
    float ssq=sm[4]+sm[5]+sm[6]+sm[7];
    t[8]=sum; t[10]=ssq;
    float tv=t[0];
    for(int k=1;k<=8;k++){ float val=(k==8)? sum : t[k]; tv = val/(sqrtf(tv)+1e-12f); }
    float c9=1.f/(sqrtf(tv)+1e-12f);
    float avn=c9*sqrtf(ssq);
    float vn=sqrtf(tv)*c9;
    float opn=avn/(vn+1e-12f);
    float sig=1.f/(1.f+__expf(-wraw[0]));
    t[19]=2.f*sig/(opn*opn);
  }
}

__global__ __launch_bounds__(256) void k_fwd_sub(const float2* __restrict__ G,
                                                 const int* __restrict__ cellArr,
                                                 const float2* __restrict__ ysub,
                                                 float4* pd){
  int j = blockIdx.x*256+threadIdx.x;
  float4 p = pd[j];
  float sx,sy;
  fwd_point(G,cellArr[j],p.x,p.y,sx,sy);
  float2 yv = ysub[j];
  pd[j]=make_float4(p.x,p.y,sx-yv.x,sy-yv.y);
}

// ---------------------------------------------------------------- composed-conv tables
// ec layout (floats): [0..99] E[oc*50+ic*25+dy*5+dx]; [100..101] C0;
// [102..119] Bb[oc*9+u]; [120..443] Btab[oc*162+u*18+ic*9+v]; [444..445] b2
__global__ __launch_bounds__(256) void k_mkE(const float* w1, const float* b1,
                                             const float* w2, const float* b2, float* ec){
  __shared__ float sw1[576], sw2[576], sb1[32], sB[324];
  int tid=threadIdx.x;
  for(int p=tid;p<576;p+=256){ sw1[p]=w1[p]; sw2[p]=w2[p]; }
  if(tid<32) sb1[tid]=b1[tid];
  __syncthreads();
  for(int e=tid;e<324;e+=256){
    int oc=e/162, r=e-oc*162, u=r/18, r2=r-u*18, ic=r2/9, v=r2-ic*9;
    float s=0.f;
    for(int cm=0;cm<32;cm++) s=fmaf(sw2[oc*288+cm*9+u], sw1[cm*18+ic*9+v], s);
    sB[e]=s; ec[120+e]=s;
  }
  if(tid<18){
    int oc=tid/9, u=tid-oc*9;
    float s=0.f;
    for(int cm=0;cm<32;cm++) s=fmaf(sw2[oc*288+cm*9+u], sb1[cm], s);
    ec[102+tid]=s;
  }
  if(tid<2){
    float s=b2[tid];
    for(int u=0;u<9;u++){
      float bb=0.f;
      for(int cm=0;cm<32;cm++) bb=fmaf(sw2[tid*288+cm*9+u], sb1[cm], bb);
      s+=bb;
    }
    ec[100+tid]=s;
    ec[444+tid]=b2[tid];
  }
  __syncthreads();
  if(tid<100){
    int oc=tid/50, r=tid-oc*50, ic=r/25, r2=r-ic*25, dy=r2/5, dx=r2-dy*5;
    float s=0.f;
    for(int uy=0;uy<3;uy++){ int vy=dy-uy; if(vy<0||vy>2) continue;
      for(int ux=0;ux<3;ux++){ int vx=dx-ux; if(vx<0||vx>2) continue;
        s+=sB[oc*162+(uy*3+ux)*18+ic*9+vy*3+vx];
      }
    }
    ec[tid]=s;
  }
}

// ---------------------------------------------------------------- fused 5x5 composed CNN + update
// blocks 0..1023: interior tiles (skip border pixels); blocks 1024..1039: border ring
#define CT_S 41
__global__ __launch_bounds__(256) void k_cnn5(const float2* __restrict__ x, const float2* __restrict__ res,
    const float* __restrict__ ec, const float* __restrict__ t,
    float2* __restrict__ xout, float* __restrict__ outPlanar){
  int tid=threadIdx.x;
  if (blockIdx.x>=1024){
    // ---- border ring: exact conv2(conv1) with h zero-masked outside image
    int id = (blockIdx.x-1024)*256+tid;   // 4096
    int py,px;
    if (id<1024){ py=0; px=id; }
    else if(id<2048){ py=1023; px=id-1024; }
    else if(id<3072){ py=id-2048; px=0; }
    else { py=id-3072; px=1023; }
    float s0=ec[444], s1=ec[445];
    for(int uy=0;uy<3;uy++){
      int qy=py+uy-1; if((unsigned)qy>=1024u) continue;
      for(int ux=0;ux<3;ux++){
        int qx=px+ux-1; if((unsigned)qx>=1024u) continue;
        int u=uy*3+ux;
        s0+=ec[102+u]; s1+=ec[111+u];
        const float* B0=&ec[120+u*18];
        const float* B1=&ec[282+u*18];
        for(int vy=0;vy<3;vy++){
          int sy2=qy+vy-1; if((unsigned)sy2>=1024u) continue;
          for(int vx=0;vx<3;vx++){
            int sx2=qx+vx-1; if((unsigned)sx2>=1024u) continue;
            int v=vy*3+vx;
            float2 xv=x[(size_t)sy2*W_+sx2];
            s0 = fmaf(B0[v],xv.x,fmaf(B0[9+v],xv.y,s0));
            s1 = fmaf(B1[v],xv.x,fmaf(B1[9+v],xv.y,s1));
          }
        }
      }
    }
    float wreg=t[19];
    size_t base=(size_t)py*W_+px;
    float2 xv=x[base], rv=res[base];
    float o0=xv.x - wreg*rv.x - s0;
    float o1=xv.y - wreg*rv.y - s1;
    if (outPlanar){ outPlanar[base]=o0; outPlanar[HW_+base]=o1; }
    else          { xout[base]=make_float2(o0,o1); }
    return;
  }
  __shared__ float xt0[36*CT_S];
  __shared__ float xt1[36*CT_S];
  __shared__ float sE[102];
  int by=blockIdx.x>>5, bx=blockIdx.x&31;
  int ty0=by<<5, tx0=bx<<5;
  for(int p=tid;p<102;p+=256) sE[p]=ec[p];
  for(int p=tid;p<1296;p+=256){
    int r=p/36, c=p-r*36;
    int gy=ty0-2+r, gx=tx0-2+c;
    float vx=0.f, vy=0.f;
    if((unsigned)gy<1024u && (unsigned)gx<1024u){ float2 v=x[(size_t)gy*W_+gx]; vx=v.x; vy=v.y; }
    xt0[r*CT_S+c]=vx; xt1[r*CT_S+c]=vy;
  }
  __syncthreads();
  int row=tid>>3, c4=(tid&7)<<2;
  float a0[4], a1[4];
  float C00=sE[100], C01=sE[101];
#pragma unroll
  for(int jj=0;jj<4;jj++){ a0[jj]=C00; a1[jj]=C01; }
#pragma unroll
  for(int dy=0;dy<5;dy++){
    const float* r0=&xt0[(row+dy)*CT_S+c4];
    const float* r1=&xt1[(row+dy)*CT_S+c4];
    float f0[9], f1[9];
#pragma unroll
    for(int q=0;q<9;q++){ f0[q]=r0[q]; f1[q]=r1[q]; }
#pragma unroll
    for(int dx=0;dx<5;dx++){
      float e00=sE[dy*5+dx], e01=sE[25+dy*5+dx];
      float e10=sE[50+dy*5+dx], e11=sE[75+dy*5+dx];
#pragma unroll
      for(int jj=0;jj<4;jj++){
        a0[jj]=fmaf(e00,f0[jj+dx],fmaf(e01,f1[jj+dx],a0[jj]));
        a1[jj]=fmaf(e10,f0[jj+dx],fmaf(e11,f1[jj+dx],a1[jj]));
      }
    }
  }
  int py=ty0+row;
  float wreg = t[19];
  size_t base=(size_t)py*W_ + tx0 + c4;
  bool rowEdge = (py==0)||(py==1023);
  if (outPlanar){
#pragma unroll
    for(int jj=0;jj<4;jj++){
      int px=tx0+c4+jj;
      if (rowEdge || px==0 || px==1023) continue;   // ring blocks own these
      float2 rv=res[base+jj];
      float xr_=xt0[(row+2)*CT_S+c4+jj+2];
      float xi_=xt1[(row+2)*CT_S+c4+jj+2];
      outPlanar[base+jj]      = xr_ - wreg*rv.x - a0[jj];
      outPlanar[HW_+base+jj]  = xi_ - wreg*rv.y - a1[jj];
    }
  } else {
#pragma unroll
    for(int jj=0;jj<4;jj++){
      int px=tx0+c4+jj;
      if (rowEdge || px==0 || px==1023) continue;
      float2 rv=res[base+jj];
      float xr_=xt0[(row+2)*CT_S+c4+jj+2];
      float xi_=xt1[(row+2)*CT_S+c4+jj+2];
      xout[base+jj]=make_float2(xr_ - wreg*rv.x - a0[jj],
                                xi_ - wreg*rv.y - a1[jj]);
    }
  }
}

// ================================================================ launch
extern "C" void kernel_launch(void* const* d_in, const int* in_sizes, int n_in,
                              void* d_out, int out_size, void* d_ws, size_t ws_size,
                              hipStream_t stream){
  (void)in_sizes; (void)n_in; (void)out_size; (void)ws_size;
  const float* xr  =(const float*)d_in[0];
  const float* xi  =(const float*)d_in[1];
  const float* kre =(const float*)d_in[2];
  const float* kim =(const float*)d_in[3];
  const float* kt  =(const float*)d_in[4];
  const float* wraw=(const float*)d_in[5];
  const float* w1  =(const float*)d_in[6];
  const float* b1  =(const float*)d_in[7];
  const float* w2  =(const float*)d_in[8];
  const float* b2  =(const float*)d_in[9];
  float* out = (float*)d_out;

  char* ws=(char*)d_ws;
  float2* Wx0 =(float2*)(ws);                      // 8MB
  float2* Wx1 =(float2*)(ws + ((size_t) 8<<20));   // 8MB
  int*   counts=(int*)   (ws + ((size_t) 8<<20));  // 4MB alias of Wx1 (setup only)
  int*   srcIdx=(int*)   (ws + ((size_t)12<<20));  // 2MB alias of Wx1 tail (setup only)
  float2* WF  =(float2*)(ws + ((size_t)16<<20));   // 8MB
  float4* pd  =(float4*)(ws + ((size_t)24<<20));   // 8MB (tx,ty,vx,vy per sorted point)
  float2* ysub=(float2*)(ws + ((size_t)32<<20));   // 4MB
  int*  cellA =(int*)   (ws + ((size_t)36<<20));   // 2MB
  int*  off   =(int*)   (ws + ((size_t)38<<20));   // 4MB
  int*  bsum  =(int*)   (ws + ((size_t)42<<20));   // 4KB
  float* t    =(float*) (ws + ((size_t)42<<20) + 8192);
  float* ec   =(float*) (ws + ((size_t)42<<20) + 16384);
  float* part =(float*) (ws + ((size_t)42<<20) + 32768);
  float* part2=(float*) (ws + ((size_t)42<<20) + 40960);
  float* pmax =(float*) (ws + ((size_t)42<<20) + 49152);
  const float SC = 0.03125f;   // 1/32 per 1-D ortho pass

  // ---- setup
  k_pack<<<HW_/256,256,0,stream>>>(xr,xi,Wx0,t);
  k_mkE<<<1,256,0,stream>>>(w1,b1,w2,b2,ec);
  hipMemsetAsync(counts,0,(size_t)HW_*sizeof(int),stream);
  k_hist<<<M_/256,256,0,stream>>>(kt,counts,pmax);
  k_reduce_max<<<1,256,0,stream>>>(pmax,t);
  k_scan1<<<1024,256,0,stream>>>(counts,off,bsum);
  k_scan2<<<1,256,0,stream>>>(bsum);
  k_scan3<<<1024,256,0,stream>>>(off,bsum);
  k_reorder1<<<M_/256,256,0,stream>>>(kt,off,srcIdx);
  k_reorder2<<<M_/256,256,0,stream>>>(srcIdx,kt,kre,kim,pd,cellA,ysub,t);

  // ---- power iteration, fully in k-space (fft2/ifft2 cancel; Parseval for norms)
  for (int n=0;n<9;n++){
    k_adj<<<HW_/1024,256,0,stream>>>(pd,off,WF,t,part,n);
    k_fwd_pow<<<M_/256,256,0,stream>>>(WF,cellA,pd,part,part2,(n==8)?1:0);
  }
  k_reduce_last<<<1,256,0,stream>>>(part,part2,wraw,t);

  // ---- npcg = 4 PGD iterations
  for (int it=0; it<4; it++){
    float2* xin  = (it&1)? Wx1 : Wx0;
    float2* xout = (it&1)? Wx0 : Wx1;
    float* planar = (it==3)? out : (float*)nullptr;
    k_fft_rows<-1><<<H_,256,0,stream>>>(xin,WF,SC);
    k_fft_cols<-1><<<W_/4,256,0,stream>>>(WF,SC);
    k_fwd_sub<<<M_/256,256,0,stream>>>(WF,cellA,ysub,pd);
    k_adj_fft<<<H_,256,0,stream>>>(pd,off,WF,SC);
    k_fft_cols<1><<<W_/4,256,0,stream>>>(WF,SC);
    k_cnn5<<<1040,256,0,stream>>>(xin,WF,ec,t,xout,planar);
  }
}

// Round 10
// 659.898 us; speedup vs baseline: 1.3246x; 1.0990x over previous
//
#include <hip/hip_runtime.h>

#define H_  1024
#define W_  1024
#define HW_ (H_*W_)
#define M_  524288

#define SWZ(a) ((a) + ((a)>>4))

// ---------------------------------------------------------------- complex mul
__device__ __forceinline__ float2 cmulf(float2 a, float2 b){
  return make_float2(fmaf(a.x,b.x,-(a.y*b.y)), fmaf(a.x,b.y,a.y*b.x));
}

// ---------------------------------------------------------------- radix-4 bfly
template<int DIR>
__device__ __forceinline__ void bfly4(float2 v[4], int j, int Ns){
  if (Ns>1){
    float ang = ((DIR>0)?6.28318530717958647692f:-6.28318530717958647692f)
                * (float)(j&(Ns-1)) / (float)(4*Ns);
    float s,c; __sincosf(ang,&s,&c);
    float2 w1=make_float2(c,s);
    float2 w2=cmulf(w1,w1);
    float2 w3=cmulf(w2,w1);
    v[1]=cmulf(v[1],w1); v[2]=cmulf(v[2],w2); v[3]=cmulf(v[3],w3);
  }
  float2 t0=make_float2(v[0].x+v[2].x, v[0].y+v[2].y);
  float2 t2=make_float2(v[0].x-v[2].x, v[0].y-v[2].y);
  float2 t1=make_float2(v[1].x+v[3].x, v[1].y+v[3].y);
  float2 t3=make_float2(v[1].x-v[3].x, v[1].y-v[3].y);
  float2 t3r=(DIR<0)?make_float2(t3.y,-t3.x):make_float2(-t3.y,t3.x);
  v[0]=make_float2(t0.x+t1.x,  t0.y+t1.y);
  v[1]=make_float2(t2.x+t3r.x, t2.y+t3r.y);
  v[2]=make_float2(t0.x-t1.x,  t0.y-t1.y);
  v[3]=make_float2(t2.x-t3r.x, t2.y-t3r.y);
}

template<int DIR, int NS>
__device__ __forceinline__ void fft_stage(int j, const float2* src, float2* dst){
  float2 v[4];
#pragma unroll
  for(int r=0;r<4;r++) v[r]=src[SWZ(j+256*r)];
  bfly4<DIR>(v,j,NS);
  int base = ((j & ~(NS-1))<<2) | (j&(NS-1));
#pragma unroll
  for(int r=0;r<4;r++) dst[SWZ(base+NS*r)]=v[r];
}

template<int DIR>
__device__ __forceinline__ void fft1024_core(float2 v[4], int j, float2* A, float2* B, float scale){
  bfly4<DIR>(v,j,1);
#pragma unroll
  for(int r=0;r<4;r++) A[SWZ(4*j+r)]=v[r];
  __syncthreads();
  fft_stage<DIR,4 >(j,A,B); __syncthreads();
  fft_stage<DIR,16>(j,B,A); __syncthreads();
  fft_stage<DIR,64>(j,A,B); __syncthreads();
#pragma unroll
  for(int r=0;r<4;r++) v[r]=B[SWZ(j+256*r)];
  bfly4<DIR>(v,j,256);
#pragma unroll
  for(int r=0;r<4;r++){ v[r].x*=scale; v[r].y*=scale; }
}

template<int DIR>
__global__ __launch_bounds__(256) void k_fft_rows(const float2* src, float2* dst, float scale){
  __shared__ float2 A[1088], B[1088];
  int j = threadIdx.x;
  const float2* s = src + (size_t)blockIdx.x*W_;
  float2 v[4];
#pragma unroll
  for(int r=0;r<4;r++) v[r]=s[j+256*r];
  fft1024_core<DIR>(v,j,A,B,scale);
  float2* d = dst + (size_t)blockIdx.x*W_;
#pragma unroll
  for(int r=0;r<4;r++) d[j+256*r]=v[r];
}

// 1 column per block, registers-direct; XCD-aware column swizzle so the 8
// columns sharing each 64B line live on one XCD's L2.
template<int DIR>
__global__ __launch_bounds__(256) void k_fft_cols1(float2* data, float scale){
  __shared__ float2 A[1088], B[1088];
  int tid=threadIdx.x;
  int col = ((blockIdx.x&7)<<7) + (blockIdx.x>>3);
  float2 v[4];
#pragma unroll
  for(int r=0;r<4;r++) v[r]=data[(size_t)(tid+256*r)*W_ + col];
  fft1024_core<DIR>(v,tid,A,B,scale);
#pragma unroll
  for(int r=0;r<4;r++) data[(size_t)(tid+256*r)*W_ + col]=v[r];
}

// ---------------------------------------------------------------- interp helpers
__device__ __forceinline__ void corners(float kx, float ky, int idx[4], float w[4]){
  float gx = kx*1024.f, gy = ky*1024.f;
  float fx = floorf(gx), fy = floorf(gy);
  float tx = gx-fx, ty = gy-fy;
  int ix = ((int)fx)&1023, iy = ((int)fy)&1023;
  int ix1=(ix+1)&1023, iy1=(iy+1)&1023;
  idx[0]=(ix<<10)|iy;  idx[1]=(ix1<<10)|iy;
  idx[2]=(ix<<10)|iy1; idx[3]=(ix1<<10)|iy1;
  float ux=1.f-tx, uy=1.f-ty;
  w[0]=ux*uy; w[1]=tx*uy; w[2]=ux*ty; w[3]=tx*ty;
}

// ---------------------------------------------------------------- adjoint accumulation for one row-strip of 4 cells
// pd[j] = (tx, ty, vx, vy) -- single 16B load per point
__device__ __forceinline__ void adj_cells4(const float4* __restrict__ pd,
                                           const int* __restrict__ off,
                                           int r, int c0,
                                           float axr[4], float ayr[4]){
#pragma unroll
  for(int q=0;q<4;q++){ axr[q]=0.f; ayr[q]=0.f; }
#pragma unroll
  for(int dr=0;dr<2;dr++){
    int br=(r-dr)&1023;
    int rowbase=br<<10;
    if (c0>0){
      int O[6];
#pragma unroll
      for(int q=0;q<6;q++) O[q]=off[rowbase+c0-2+q];
#pragma unroll
      for(int i=0;i<5;i++){
        for(int j=O[i]; j<O[i+1]; j++){
          float4 p=pd[j];
          float wx = dr ? p.x : 1.f-p.x;
          float w0 = wx*(1.f-p.y), w1 = wx*p.y;
          if (i>=1){ axr[i-1]=fmaf(w0,p.z,axr[i-1]); ayr[i-1]=fmaf(w0,p.w,ayr[i-1]); }
          if (i<=3){ axr[i]  =fmaf(w1,p.z,axr[i]);   ayr[i]  =fmaf(w1,p.w,ayr[i]); }
        }
      }
    } else {
      int bw = rowbase+1023;
      int sw = off[bw-1], ew=off[bw];
      for(int j=sw;j<ew;j++){
        float4 p=pd[j];
        float wx = dr ? p.x : 1.f-p.x;
        float w1 = wx*p.y;
        axr[0]=fmaf(w1,p.z,axr[0]); ayr[0]=fmaf(w1,p.w,ayr[0]);
      }
      int O[5];
      O[0] = (rowbase==0)? 0 : off[rowbase-1];
#pragma unroll
      for(int q=1;q<5;q++) O[q]=off[rowbase+q-1];
#pragma unroll
      for(int i=0;i<4;i++){
        for(int j=O[i]; j<O[i+1]; j++){
          float4 p=pd[j];
          float wx = dr ? p.x : 1.f-p.x;
          float w0 = wx*(1.f-p.y), w1 = wx*p.y;
          axr[i]=fmaf(w0,p.z,axr[i]); ayr[i]=fmaf(w0,p.w,ayr[i]);
          if (i<=2){ axr[i+1]=fmaf(w1,p.z,axr[i+1]); ayr[i+1]=fmaf(w1,p.w,ayr[i+1]); }
        }
      }
    }
  }
}

// ---------------------------------------------------------------- init
__global__ __launch_bounds__(256) void k_pack(const float* xr, const float* xi, float2* X, float* t){
  int i = blockIdx.x*256+threadIdx.x;
  if (i<HW_) X[i]=make_float2(xr[i],xi[i]);
  if (blockIdx.x==0 && threadIdx.x<32) t[threadIdx.x]=0.f;
}

__global__ __launch_bounds__(256) void k_hist(const float* kt, int* counts, float* pmax){
  int m = blockIdx.x*256+threadIdx.x;
  float r = 0.f;
  {
    float kx=kt[2*m], ky=kt[2*m+1];
    float dx=kx-0.5f, dy=ky-0.5f;
    r = sqrtf(dx*dx+dy*dy);
    int ix = ((int)floorf(kx*1024.f))&1023;
    int iy = ((int)floorf(ky*1024.f))&1023;
    atomicAdd(&counts[(ix<<10)|iy],1);
  }
  for(int o=32;o>0;o>>=1) r = fmaxf(r, __shfl_down(r,o,64));
  __shared__ float sm[4];
  if((threadIdx.x&63)==0) sm[threadIdx.x>>6]=r;
  __syncthreads();
  if(threadIdx.x==0)
    pmax[blockIdx.x] = fmaxf(fmaxf(sm[0],sm[1]),fmaxf(sm[2],sm[3]));
}

__global__ __launch_bounds__(256) void k_reduce_max(const float* pmax, float* t){
  int tid=threadIdx.x;
  float s=-1e30f;
  for(int k=tid;k<2048;k+=256) s=fmaxf(s,pmax[k]);
  __shared__ float sm[4];
  for(int o=32;o>0;o>>=1) s=fmaxf(s,__shfl_down(s,o,64));
  if((tid&63)==0) sm[tid>>6]=s;
  __syncthreads();
  if(tid==0) t[15]=fmaxf(fmaxf(sm[0],sm[1]),fmaxf(sm[2],sm[3]));
}

// ---------------------------------------------------------------- scan
__global__ __launch_bounds__(256) void k_scan1(const int* cnt, int* off, int* bsum){
  __shared__ int sm[256];
  int base = blockIdx.x*1024;
  int tid = threadIdx.x;
  int4 c = *(const int4*)(cnt + base + tid*4);
  int s = c.x+c.y+c.z+c.w;
  sm[tid]=s; __syncthreads();
  int v=s;
  for(int o=1;o<256;o<<=1){
    int u = (tid>=o)? sm[tid-o]:0;
    __syncthreads();
    v += u; sm[tid]=v;
    __syncthreads();
  }
  int excl = v - s;
  int4 o4;
  o4.x=excl; o4.y=excl+c.x; o4.z=excl+c.x+c.y; o4.w=excl+c.x+c.y+c.z;
  *(int4*)(off+base+tid*4)=o4;
  if (tid==255) bsum[blockIdx.x]=v;
}

__global__ __launch_bounds__(256) void k_scan2(int* bsum){
  __shared__ int sm[256];
  int tid=threadIdx.x;
  int4 c = *(const int4*)(bsum + tid*4);
  int s = c.x+c.y+c.z+c.w;
  sm[tid]=s; __syncthreads();
  int v=s;
  for(int o=1;o<256;o<<=1){
    int u = (tid>=o)? sm[tid-o]:0;
    __syncthreads();
    v += u; sm[tid]=v;
    __syncthreads();
  }
  int excl=v-s;
  int4 o4;
  o4.x=excl; o4.y=excl+c.x; o4.z=excl+c.x+c.y; o4.w=excl+c.x+c.y+c.z;
  *(int4*)(bsum+tid*4)=o4;
}

__global__ __launch_bounds__(256) void k_scan3(int* off, const int* bbase){
  int gid = blockIdx.x*256+threadIdx.x;
  int b = bbase[gid>>8];
  int4 v = *(int4*)(off + gid*4);
  v.x+=b; v.y+=b; v.z+=b; v.w+=b;
  *(int4*)(off + gid*4)=v;
}

// ---------------------------------------------------------------- reorder (2-pass)
__global__ __launch_bounds__(256) void k_reorder1(const float* kt, int* off, int* srcIdx){
  int m = blockIdx.x*256+threadIdx.x;
  float kx=kt[2*m], ky=kt[2*m+1];
  int ix=((int)floorf(kx*1024.f))&1023;
  int iy=((int)floorf(ky*1024.f))&1023;
  int pos = atomicAdd(&off[(ix<<10)|iy],1);
  srcIdx[pos]=m;
}

__global__ __launch_bounds__(256) void k_reorder2(const int* srcIdx, const float* kt,
                                                  const float* kre, const float* kim,
                                                  float4* pd, int* cellArr,
                                                  float2* ysub, const float* t){
  int p = blockIdx.x*256+threadIdx.x;
  int m = srcIdx[p];
  float kx=kt[2*m], ky=kt[2*m+1];
  float gx=kx*1024.f, gy=ky*1024.f;
  float fx=floorf(gx), fy=floorf(gy);
  float tx=gx-fx, ty=gy-fy;
  int ix=((int)fx)&1023, iy=((int)fy)&1023;
  cellArr[p]=(ix<<10)|iy;
  float dx=kx-0.5f, dy=ky-0.5f;
  float r=sqrtf(dx*dx+dy*dy);
  float dcf=sqrtf(r/(t[15]+1e-8f));
  ysub[p]=make_float2(kre[m]*dcf, kim[m]*dcf);
  // av0 = gather(fft2(ones)): weights whose target cell is (0,0)
  int idx[4]; float w[4];
  corners(kx,ky,idx,w);
  float s=0.f;
#pragma unroll
  for(int q=0;q<4;q++) if (idx[q]==0) s+=w[q];
  pd[p]=make_float4(tx,ty,1024.f*s,0.f);
}

// ---------------------------------------------------------------- adjoint (power phase): flat grid, 4 cells/thread,
// chain-reduce folded in (each block redundantly sums part[2048] -> sc; block 0 persists t[chain_n-1])
__global__ __launch_bounds__(256) void k_adj(const float4* __restrict__ pd,
                                             const int* __restrict__ off,
                                             float2* __restrict__ G,
                                             float* t, const float* __restrict__ part,
                                             int chain_n){
  __shared__ float sm[4];
  __shared__ float scv;
  int tid=threadIdx.x;
  float sc=1.f;
  if (chain_n>0){
    float s=0.f;
    for(int k=tid;k<2048;k+=256) s+=part[k];
    for(int o=32;o>0;o>>=1) s+=__shfl_down(s,o,64);
    if((tid&63)==0) sm[tid>>6]=s;
    __syncthreads();
    if(tid==0){
      float dot=sm[0]+sm[1]+sm[2]+sm[3];
      float tv;
      if (chain_n==1) tv=dot;
      else {
        tv=t[0];
        for(int k=1;k<chain_n-1;k++) tv = t[k]/(sqrtf(tv)+1e-12f);
        tv = dot/(sqrtf(tv)+1e-12f);
      }
      scv = 1.f/(sqrtf(tv)+1e-12f);
      if (blockIdx.x==0) t[chain_n-1]=dot;
    }
    __syncthreads();
    sc=scv;
  }
  int gid = blockIdx.x*256+tid;
  int r  = gid>>8;
  int c0 = (gid&255)<<2;
  float axr[4], ayr[4];
  adj_cells4(pd,off,r,c0,axr,ayr);
  size_t base=((size_t)r<<10)+c0;
#pragma unroll
  for(int q=0;q<4;q++) G[base+q]=make_float2(axr[q]*sc, ayr[q]*sc);
}

// ---------------------------------------------------------------- adjoint + row-FFT fused (npcg phase): block = grid row
__global__ __launch_bounds__(256) void k_adj_fft(const float4* __restrict__ pd,
                                                 const int* __restrict__ off,
                                                 float2* __restrict__ WF, float scale){
  __shared__ float2 X[1024];
  __shared__ float2 A[1088], B[1088];
  int r = blockIdx.x, tid=threadIdx.x;
  int c0 = tid<<2;
  float axr[4], ayr[4];
  adj_cells4(pd,off,r,c0,axr,ayr);
#pragma unroll
  for(int q=0;q<4;q++) X[c0+q]=make_float2(axr[q],ayr[q]);
  __syncthreads();
  float2 v[4];
#pragma unroll
  for(int rr=0;rr<4;rr++) v[rr]=X[tid+256*rr];
  fft1024_core<1>(v,tid,A,B,scale);
  float2* d = WF + ((size_t)r<<10);
#pragma unroll
  for(int rr=0;rr<4;rr++) d[tid+256*rr]=v[rr];
}

// ---------------------------------------------------------------- forward gather
__device__ __forceinline__ void fwd_point(const float2* __restrict__ G, int cellv, float tx, float ty,
                                          float& sx, float& sy){
  int ix=cellv>>10, iy=cellv&1023;
  int ix1=(ix+1)&1023, iy1=(iy+1)&1023;
  float ux=1.f-tx, uy=1.f-ty;
  float2 g00=G[(ix<<10)|iy], g10=G[(ix1<<10)|iy], g01=G[(ix<<10)|iy1], g11=G[(ix1<<10)|iy1];
  float w0=ux*uy, w1=tx*uy, w2=ux*ty, w3=tx*ty;
  sx = fmaf(w0,g00.x,fmaf(w1,g10.x,fmaf(w2,g01.x,w3*g11.x)));
  sy = fmaf(w0,g00.y,fmaf(w1,g10.y,fmaf(w2,g01.y,w3*g11.y)));
}

__global__ __launch_bounds__(256) void k_fwd_pow(const float2* __restrict__ G,
                                                 const int* __restrict__ cellArr,
                                                 float4* pd, float* part, float* part2, int last){
  int j = blockIdx.x*256+threadIdx.x;
  float dot, ssq;
  {
    float4 p = pd[j];
    float sx,sy;
    fwd_point(G,cellArr[j],p.x,p.y,sx,sy);
    dot = sx*p.z + sy*p.w;
    ssq = sx*sx + sy*sy;
    pd[j]=make_float4(p.x,p.y,sx,sy);
  }
  __shared__ float sm[4];
  for(int o=32;o>0;o>>=1) dot += __shfl_down(dot,o,64);
  if((threadIdx.x&63)==0) sm[threadIdx.x>>6]=dot;
  __syncthreads();
  if(threadIdx.x==0) part[blockIdx.x]=sm[0]+sm[1]+sm[2]+sm[3];
  if (last){
    __syncthreads();
    for(int o=32;o>0;o>>=1) ssq += __shfl_down(ssq,o,64);
    if((threadIdx.x&63)==0) sm[threadIdx.x>>6]=ssq;
    __syncthreads();
    if(threadIdx.x==0) part2[blockIdx.x]=sm[0]+sm[1]+sm[2]+sm[3];
  }
}

__global__ __launch_bounds__(256) void k_reduce_last(const float* part, const float* part2,
                                                     const float* wraw, float* t){
  int tid=threadIdx.x;
  float s1=0.f, s2=0.f;
  for(int k=tid;k<2048;k+=256){ s1+=part[k]; s2+=part2[k]; }
  __shared__ float sm[8];
  for(int o=32;o>0;o>>=1){ s1+=__shfl_down(s1,o,64); s2+=__shfl_down(s2,o,64); }
  if((tid&63)==0){ sm[tid>>6]=s1; sm[4+(tid>>6)]=s2; }
  __syncthreads();
  if(tid==0){
    float sum=sm[0]+sm[1]+sm[2]+sm[3];
    float ssq=sm[4]+sm[5]+sm[6]+sm[7];
    t[8]=sum; t[10]=ssq;
    float tv=t[0];
    for(int k=1;k<=8;k++){ float val=(k==8)? sum : t[k]; tv = val/(sqrtf(tv)+1e-12f); }
    float c9=1.f/(sqrtf(tv)+1e-12f);
    float avn=c9*sqrtf(ssq);
    float vn=sqrtf(tv)*c9;
    float opn=avn/(vn+1e-12f);
    float sig=1.f/(1.f+__expf(-wraw[0]));
    t[19]=2.f*sig/(opn*opn);
  }
}

__global__ __launch_bounds__(256) void k_fwd_sub(const float2* __restrict__ G,
                                                 const int* __restrict__ cellArr,
                                                 const float2* __restrict__ ysub,
                                                 float4* pd){
  int j = blockIdx.x*256+threadIdx.x;
  float4 p = pd[j];
  float sx,sy;
  fwd_point(G,cellArr[j],p.x,p.y,sx,sy);
  float2 yv = ysub[j];
  pd[j]=make_float4(p.x,p.y,sx-yv.x,sy-yv.y);
}

// ---------------------------------------------------------------- composed-conv tables
// ec layout (floats): [0..99] E[oc*50+ic*25+dy*5+dx]; [100..101] C0;
// [102..119] Bb[oc*9+u]; [120..443] Btab[oc*162+u*18+ic*9+v]; [444..445] b2
__global__ __launch_bounds__(256) void k_mkE(const float* w1, const float* b1,
                                             const float* w2, const float* b2, float* ec){
  __shared__ float sw1[576], sw2[576], sb1[32], sB[324];
  int tid=threadIdx.x;
  for(int p=tid;p<576;p+=256){ sw1[p]=w1[p]; sw2[p]=w2[p]; }
  if(tid<32) sb1[tid]=b1[tid];
  __syncthreads();
  for(int e=tid;e<324;e+=256){
    int oc=e/162, r=e-oc*162, u=r/18, r2=r-u*18, ic=r2/9, v=r2-ic*9;
    float s=0.f;
    for(int cm=0;cm<32;cm++) s=fmaf(sw2[oc*288+cm*9+u], sw1[cm*18+ic*9+v], s);
    sB[e]=s; ec[120+e]=s;
  }
  if(tid<18){
    int oc=tid/9, u=tid-oc*9;
    float s=0.f;
    for(int cm=0;cm<32;cm++) s=fmaf(sw2[oc*288+cm*9+u], sb1[cm], s);
    ec[102+tid]=s;
  }
  if(tid<2){
    float s=b2[tid];
    for(int u=0;u<9;u++){
      float bb=0.f;
      for(int cm=0;cm<32;cm++) bb=fmaf(sw2[tid*288+cm*9+u], sb1[cm], bb);
      s+=bb;
    }
    ec[100+tid]=s;
    ec[444+tid]=b2[tid];
  }
  __syncthreads();
  if(tid<100){
    int oc=tid/50, r=tid-oc*50, ic=r/25, r2=r-ic*25, dy=r2/5, dx=r2-dy*5;
    float s=0.f;
    for(int uy=0;uy<3;uy++){ int vy=dy-uy; if(vy<0||vy>2) continue;
      for(int ux=0;ux<3;ux++){ int vx=dx-ux; if(vx<0||vx>2) continue;
        s+=sB[oc*162+(uy*3+ux)*18+ic*9+vy*3+vx];
      }
    }
    ec[tid]=s;
  }
}

// ---------------------------------------------------------------- fused 5x5 composed CNN + update
// blocks 0..1023: interior tiles (skip border pixels); blocks 1024..1039: border ring
#define CT_S 41
__global__ __launch_bounds__(256) void k_cnn5(const float2* __restrict__ x, const float2* __restrict__ res,
    const float* __restrict__ ec, const float* __restrict__ t,
    float2* __restrict__ xout, float* __restrict__ outPlanar){
  int tid=threadIdx.x;
  if (blockIdx.x>=1024){
    // ---- border ring: exact conv2(conv1) with h zero-masked outside image
    int id = (blockIdx.x-1024)*256+tid;   // 4096
    int py,px;
    if (id<1024){ py=0; px=id; }
    else if(id<2048){ py=1023; px=id-1024; }
    else if(id<3072){ py=id-2048; px=0; }
    else { py=id-3072; px=1023; }
    float s0=ec[444], s1=ec[445];
    for(int uy=0;uy<3;uy++){
      int qy=py+uy-1; if((unsigned)qy>=1024u) continue;
      for(int ux=0;ux<3;ux++){
        int qx=px+ux-1; if((unsigned)qx>=1024u) continue;
        int u=uy*3+ux;
        s0+=ec[102+u]; s1+=ec[111+u];
        const float* B0=&ec[120+u*18];
        const float* B1=&ec[282+u*18];
        for(int vy=0;vy<3;vy++){
          int sy2=qy+vy-1; if((unsigned)sy2>=1024u) continue;
          for(int vx=0;vx<3;vx++){
            int sx2=qx+vx-1; if((unsigned)sx2>=1024u) continue;
            int v=vy*3+vx;
            float2 xv=x[(size_t)sy2*W_+sx2];
            s0 = fmaf(B0[v],xv.x,fmaf(B0[9+v],xv.y,s0));
            s1 = fmaf(B1[v],xv.x,fmaf(B1[9+v],xv.y,s1));
          }
        }
      }
    }
    float wreg=t[19];
    size_t base=(size_t)py*W_+px;
    float2 xv=x[base], rv=res[base];
    float o0=xv.x - wreg*rv.x - s0;
    float o1=xv.y - wreg*rv.y - s1;
    if (outPlanar){ outPlanar[base]=o0; outPlanar[HW_+base]=o1; }
    else          { xout[base]=make_float2(o0,o1); }
    return;
  }
  __shared__ float xt0[36*CT_S];
  __shared__ float xt1[36*CT_S];
  __shared__ float sE[102];
  int by=blockIdx.x>>5, bx=blockIdx.x&31;
  int ty0=by<<5, tx0=bx<<5;
  for(int p=tid;p<102;p+=256) sE[p]=ec[p];
  for(int p=tid;p<1296;p+=256){
    int r=p/36, c=p-r*36;
    int gy=ty0-2+r, gx=tx0-2+c;
    float vx=0.f, vy=0.f;
    if((unsigned)gy<1024u && (unsigned)gx<1024u){ float2 v=x[(size_t)gy*W_+gx]; vx=v.x; vy=v.y; }
    xt0[r*CT_S+c]=vx; xt1[r*CT_S+c]=vy;
  }
  __syncthreads();
  int row=tid>>3, c4=(tid&7)<<2;
  float a0[4], a1[4];
  float C00=sE[100], C01=sE[101];
#pragma unroll
  for(int jj=0;jj<4;jj++){ a0[jj]=C00; a1[jj]=C01; }
#pragma unroll
  for(int dy=0;dy<5;dy++){
    const float* r0=&xt0[(row+dy)*CT_S+c4];
    const float* r1=&xt1[(row+dy)*CT_S+c4];
    float f0[9], f1[9];
#pragma unroll
    for(int q=0;q<9;q++){ f0[q]=r0[q]; f1[q]=r1[q]; }
#pragma unroll
    for(int dx=0;dx<5;dx++){
      float e00=sE[dy*5+dx], e01=sE[25+dy*5+dx];
      float e10=sE[50+dy*5+dx], e11=sE[75+dy*5+dx];
#pragma unroll
      for(int jj=0;jj<4;jj++){
        a0[jj]=fmaf(e00,f0[jj+dx],fmaf(e01,f1[jj+dx],a0[jj]));
        a1[jj]=fmaf(e10,f0[jj+dx],fmaf(e11,f1[jj+dx],a1[jj]));
      }
    }
  }
  int py=ty0+row;
  float wreg = t[19];
  size_t base=(size_t)py*W_ + tx0 + c4;
  bool rowEdge = (py==0)||(py==1023);
  if (outPlanar){
#pragma unroll
    for(int jj=0;jj<4;jj++){
      int px=tx0+c4+jj;
      if (rowEdge || px==0 || px==1023) continue;   // ring blocks own these
      float2 rv=res[base+jj];
      float xr_=xt0[(row+2)*CT_S+c4+jj+2];
      float xi_=xt1[(row+2)*CT_S+c4+jj+2];
      outPlanar[base+jj]      = xr_ - wreg*rv.x - a0[jj];
      outPlanar[HW_+base+jj]  = xi_ - wreg*rv.y - a1[jj];
    }
  } else {
#pragma unroll
    for(int jj=0;jj<4;jj++){
      int px=tx0+c4+jj;
      if (rowEdge || px==0 || px==1023) continue;
      float2 rv=res[base+jj];
      float xr_=xt0[(row+2)*CT_S+c4+jj+2];
      float xi_=xt1[(row+2)*CT_S+c4+jj+2];
      xout[base+jj]=make_float2(xr_ - wreg*rv.x - a0[jj],
                                xi_ - wreg*rv.y - a1[jj]);
    }
  }
}

// ================================================================ launch
extern "C" void kernel_launch(void* const* d_in, const int* in_sizes, int n_in,
                              void* d_out, int out_size, void* d_ws, size_t ws_size,
                              hipStream_t stream){
  (void)in_sizes; (void)n_in; (void)out_size; (void)ws_size;
  const float* xr  =(const float*)d_in[0];
  const float* xi  =(const float*)d_in[1];
  const float* kre =(const float*)d_in[2];
  const float* kim =(const float*)d_in[3];
  const float* kt  =(const float*)d_in[4];
  const float* wraw=(const float*)d_in[5];
  const float* w1  =(const float*)d_in[6];
  const float* b1  =(const float*)d_in[7];
  const float* w2  =(const float*)d_in[8];
  const float* b2  =(const float*)d_in[9];
  float* out = (float*)d_out;

  char* ws=(char*)d_ws;
  float2* Wx0 =(float2*)(ws);                      // 8MB
  float2* Wx1 =(float2*)(ws + ((size_t) 8<<20));   // 8MB
  int*   counts=(int*)   (ws + ((size_t) 8<<20));  // 4MB alias of Wx1 (setup only)
  int*   srcIdx=(int*)   (ws + ((size_t)12<<20));  // 2MB alias of Wx1 tail (setup only)
  float2* WF  =(float2*)(ws + ((size_t)16<<20));   // 8MB
  float4* pd  =(float4*)(ws + ((size_t)24<<20));   // 8MB (tx,ty,vx,vy per sorted point)
  float2* ysub=(float2*)(ws + ((size_t)32<<20));   // 4MB
  int*  cellA =(int*)   (ws + ((size_t)36<<20));   // 2MB
  int*  off   =(int*)   (ws + ((size_t)38<<20));   // 4MB
  int*  bsum  =(int*)   (ws + ((size_t)42<<20));   // 4KB
  float* t    =(float*) (ws + ((size_t)42<<20) + 8192);
  float* ec   =(float*) (ws + ((size_t)42<<20) + 16384);
  float* part =(float*) (ws + ((size_t)42<<20) + 32768);
  float* part2=(float*) (ws + ((size_t)42<<20) + 40960);
  float* pmax =(float*) (ws + ((size_t)42<<20) + 49152);
  const float SC = 0.03125f;   // 1/32 per 1-D ortho pass

  // ---- setup
  k_pack<<<HW_/256,256,0,stream>>>(xr,xi,Wx0,t);
  k_mkE<<<1,256,0,stream>>>(w1,b1,w2,b2,ec);
  hipMemsetAsync(counts,0,(size_t)HW_*sizeof(int),stream);
  k_hist<<<M_/256,256,0,stream>>>(kt,counts,pmax);
  k_reduce_max<<<1,256,0,stream>>>(pmax,t);
  k_scan1<<<1024,256,0,stream>>>(counts,off,bsum);
  k_scan2<<<1,256,0,stream>>>(bsum);
  k_scan3<<<1024,256,0,stream>>>(off,bsum);
  k_reorder1<<<M_/256,256,0,stream>>>(kt,off,srcIdx);
  k_reorder2<<<M_/256,256,0,stream>>>(srcIdx,kt,kre,kim,pd,cellA,ysub,t);

  // ---- power iteration, fully in k-space (fft2/ifft2 cancel; Parseval for norms)
  for (int n=0;n<9;n++){
    k_adj<<<HW_/1024,256,0,stream>>>(pd,off,WF,t,part,n);
    k_fwd_pow<<<M_/256,256,0,stream>>>(WF,cellA,pd,part,part2,(n==8)?1:0);
  }
  k_reduce_last<<<1,256,0,stream>>>(part,part2,wraw,t);

  // ---- npcg = 4 PGD iterations
  for (int it=0; it<4; it++){
    float2* xin  = (it&1)? Wx1 : Wx0;
    float2* xout = (it&1)? Wx0 : Wx1;
    float* planar = (it==3)? out : (float*)nullptr;
    k_fft_rows<-1><<<H_,256,0,stream>>>(xin,WF,SC);
    k_fft_cols1<-1><<<H_,256,0,stream>>>(WF,SC);
    k_fwd_sub<<<M_/256,256,0,stream>>>(WF,cellA,ysub,pd);
    k_adj_fft<<<H_,256,0,stream>>>(pd,off,WF,SC);
    k_fft_cols1<1><<<H_,256,0,stream>>>(WF,SC);
    k_cnn5<<<1040,256,0,stream>>>(xin,WF,ec,t,xout,planar);
  }
}